// Round 2
// 1204.167 us; speedup vs baseline: 1.0233x; 1.0233x over previous
//
#include <hip/hip_runtime.h>
#include <hip/hip_bf16.h>
#include <math.h>

#define Bq 64
#define Sq 300
#define NH 4
#define DHd 32
#define Dd 128
#define NL 8
#define FF 512
#define NIN 36
#define SP 304   // padded seq for MFMA tiles

typedef __attribute__((ext_vector_type(8))) short bf16x8;
typedef __attribute__((ext_vector_type(4))) float f32x4;

__device__ __forceinline__ float gelu_f(float x) {
    return 0.5f * x * (1.0f + erff(x * 0.70710678118654752f));
}
__device__ __forceinline__ bool bf16_mode(const unsigned* maskw) {
    return maskw[0] == 0x3F803F80u;   // two bf16 1.0s; f32 1.0 is 0x3F800000
}

// -------- dtype-agnostic input widening: all 36 inputs -> fp32 shadow in ws --------
struct ConvArgs {
    const void* src[NIN];
    float* dst[NIN];
    int n[NIN];
};

__global__ void convert_kernel(ConvArgs a, const unsigned* maskw) {
    bool bfm = bf16_mode(maskw);
    int bi = blockIdx.y;
    int n = a.n[bi];
    float* dst = a.dst[bi];
    int stride = gridDim.x * blockDim.x;
    int i0 = blockIdx.x * blockDim.x + threadIdx.x;
    if (bfm) {
        const __hip_bfloat16* s = (const __hip_bfloat16*)a.src[bi];
        for (int i = i0; i < n; i += stride) dst[i] = __bfloat162float(s[i]);
    } else {
        const float* s = (const float*)a.src[bi];
        for (int i = i0; i < n; i += stride) dst[i] = s[i];
    }
}

// -------- pack weights to MFMA B-operand layout [nt][kt][64][8] bf16 --------
// which: 0=ffn_W1(K128,N512) 1=ffn_W2(K512,N128) 2=qkv_W(K128,N384)
//        3=attn_out_W(K128,N128) 4=rec_W1(K128,N128,l=0) 5=rec_W2(K128,N64,l=0)
__global__ void pack_kernel(const float* __restrict__ W1all, const float* __restrict__ W2all,
                            const float* __restrict__ Wqall, const float* __restrict__ Woall,
                            const float* __restrict__ Wr1, const float* __restrict__ Wr2,
                            __hip_bfloat16* __restrict__ P1, __hip_bfloat16* __restrict__ P2,
                            __hip_bfloat16* __restrict__ Pq, __hip_bfloat16* __restrict__ Po,
                            __hip_bfloat16* __restrict__ Pr1, __hip_bfloat16* __restrict__ Pr2) {
    int l = blockIdx.y;
    int which = blockIdx.z;
    if (which >= 4 && l != 0) return;
    int K = (which == 1) ? 512 : 128;
    int N = (which == 0) ? 512 : (which == 1 ? 128 : (which == 2 ? 384 : (which == 5 ? 64 : 128)));
    int slots = (K / 32) * (N / 16) * 64;
    int idx = blockIdx.x * 256 + threadIdx.x;
    if (idx >= slots) return;
    int lane = idx & 63;
    int nkt = K / 32;
    int kt = (idx >> 6) % nkt;
    int nt = (idx >> 6) / nkt;
    const float* W; __hip_bfloat16* P;
    switch (which) {
        case 0:  W = W1all + (size_t)l * 128 * 512; P = P1 + (size_t)l * 65536; break;
        case 1:  W = W2all + (size_t)l * 512 * 128; P = P2 + (size_t)l * 65536; break;
        case 2:  W = Wqall + (size_t)l * 128 * 384; P = Pq + (size_t)l * 49152; break;
        case 3:  W = Woall + (size_t)l * 128 * 128; P = Po + (size_t)l * 16384; break;
        case 4:  W = Wr1; P = Pr1; break;
        default: W = Wr2; P = Pr2; break;
    }
    P += (size_t)idx * 8;
    int n = nt * 16 + (lane & 15);
    int k0 = kt * 32 + (lane >> 4) * 8;
    #pragma unroll
    for (int j = 0; j < 8; j++) P[j] = __float2bfloat16(W[(size_t)(k0 + j) * N + n]);
}

// -------- embedding v2: 16 rows/block, fp32 VALU, shuffle-LN --------
// MLP(3->64->128->128) + tok_emb + LN + mask. 8 indep accumulators/thread,
// float4 weight loads (L1 broadcast), LN via 16-lane shfl groups.
__global__ __launch_bounds__(256) void embed16_kernel(const float* __restrict__ inp, const float* __restrict__ mask,
                              const float* __restrict__ W1, const float* __restrict__ b1,
                              const float* __restrict__ W2, const float* __restrict__ b2,
                              const float* __restrict__ W3, const float* __restrict__ b3,
                              const float* __restrict__ tok_emb,
                              const float* __restrict__ ln_s, const float* __restrict__ ln_b,
                              float* __restrict__ x) {
    int blk = blockIdx.x;        // 0..1199
    int t = threadIdx.x;         // 0..255
    int row0 = blk * 16;
    __shared__ float f[16][4];
    __shared__ float e1s[16][68];   // +4 pad: spread 4-row broadcasts across banks
    __shared__ float e2s[16][132];
    if (t < 64) f[t >> 2][t & 3] = inp[(size_t)(row0 + (t >> 2)) * 4 + (t & 3)];
    __syncthreads();
    {   // layer1: 3->64, 4 outputs/thread
        int r1 = t >> 4, n0 = (t & 15) * 4;
        float f0 = f[r1][0], f1 = f[r1][1], f2 = f[r1][2];
        #pragma unroll
        for (int j = 0; j < 4; j++) {
            int n = n0 + j;
            float a = b1[n] + f0 * W1[n] + f1 * W1[64 + n] + f2 * W1[128 + n];
            e1s[r1][n] = gelu_f(a);
        }
    }
    __syncthreads();
    int r = t >> 4, cg = (t & 15) * 8;   // thread owns row r, cols [cg, cg+8)
    {   // layer2: 64->128
        float acc[8];
        #pragma unroll
        for (int j = 0; j < 8; j++) acc[j] = b2[cg + j];
        #pragma unroll 4
        for (int kk = 0; kk < 64; kk++) {
            float ev = e1s[r][kk];
            float4 w0 = *(const float4*)&W2[kk * 128 + cg];
            float4 w1 = *(const float4*)&W2[kk * 128 + cg + 4];
            acc[0] += ev * w0.x; acc[1] += ev * w0.y; acc[2] += ev * w0.z; acc[3] += ev * w0.w;
            acc[4] += ev * w1.x; acc[5] += ev * w1.y; acc[6] += ev * w1.z; acc[7] += ev * w1.w;
        }
        #pragma unroll
        for (int j = 0; j < 8; j++) e2s[r][cg + j] = gelu_f(acc[j]);
    }
    __syncthreads();
    float y[8];
    {   // layer3: 128->128 + tok_emb
        float acc[8];
        #pragma unroll
        for (int j = 0; j < 8; j++) acc[j] = b3[cg + j];
        #pragma unroll 4
        for (int kk = 0; kk < 128; kk++) {
            float ev = e2s[r][kk];
            float4 w0 = *(const float4*)&W3[kk * 128 + cg];
            float4 w1 = *(const float4*)&W3[kk * 128 + cg + 4];
            acc[0] += ev * w0.x; acc[1] += ev * w0.y; acc[2] += ev * w0.z; acc[3] += ev * w0.w;
            acc[4] += ev * w1.x; acc[5] += ev * w1.y; acc[6] += ev * w1.z; acc[7] += ev * w1.w;
        }
        int tok = (int)f[r][3];
        #pragma unroll
        for (int j = 0; j < 8; j++) y[j] = gelu_f(acc[j]) + tok_emb[tok * 128 + cg + j];
    }
    // LN across the row: 16 consecutive lanes own one row (aligned 16-groups)
    float sm = 0.f;
    #pragma unroll
    for (int j = 0; j < 8; j++) sm += y[j];
    sm += __shfl_xor(sm, 1); sm += __shfl_xor(sm, 2); sm += __shfl_xor(sm, 4); sm += __shfl_xor(sm, 8);
    float mu = sm * (1.0f / 128.0f);
    float vv = 0.f;
    #pragma unroll
    for (int j = 0; j < 8; j++) { y[j] -= mu; vv += y[j] * y[j]; }
    vv += __shfl_xor(vv, 1); vv += __shfl_xor(vv, 2); vv += __shfl_xor(vv, 4); vv += __shfl_xor(vv, 8);
    float rstd = rsqrtf(vv * (1.0f / 128.0f) + 1e-7f);
    float mk = mask[row0 + r];
    float o[8];
    #pragma unroll
    for (int j = 0; j < 8; j++) o[j] = (y[j] * rstd * ln_s[cg + j] + ln_b[cg + j]) * mk;
    *(float4*)&x[(size_t)(row0 + r) * 128 + cg] = *(float4*)&o[0];
    *(float4*)&x[(size_t)(row0 + r) * 128 + cg + 4] = *(float4*)&o[4];
}

// -------- qkv via MFMA: also emits bf16 q/k [bh][SP][32] and vT [bh][32][SP] --------
__global__ __launch_bounds__(256) void qkv_mfma_kernel(const float* __restrict__ x,
                                                       const __hip_bfloat16* __restrict__ Pq,
                                                       const float* __restrict__ qb, const float* __restrict__ vb,
                                                       float* __restrict__ q, float* __restrict__ k,
                                                       __hip_bfloat16* __restrict__ qbf,
                                                       __hip_bfloat16* __restrict__ kbf,
                                                       __hip_bfloat16* __restrict__ vT) {
    int blk = blockIdx.x;       // 0..1199
    int t = threadIdx.x;        // 0..255
    int w = t >> 6, lane = t & 63;
    int row0 = blk * 16;
    __shared__ __align__(16) __hip_bfloat16 xa[16 * 136];
    for (int i = t; i < 512; i += 256) {
        float4 v4 = ((const float4*)(x + (size_t)row0 * 128))[i];
        int r = i >> 5, c4 = (i & 31) * 4;
        __hip_bfloat16* d = &xa[r * 136 + c4];
        d[0] = __float2bfloat16(v4.x); d[1] = __float2bfloat16(v4.y);
        d[2] = __float2bfloat16(v4.z); d[3] = __float2bfloat16(v4.w);
    }
    __syncthreads();
    int m = lane & 15, quad = lane >> 4;
    bf16x8 a1[4];
    #pragma unroll
    for (int kt = 0; kt < 4; kt++) a1[kt] = *(bf16x8*)&xa[m * 136 + kt * 32 + quad * 8];
    const float inv_scale = 0.10206207261596576f;  // 1/sqrt(96)
    #pragma unroll
    for (int nt0 = 0; nt0 < 6; nt0++) {
        int nt = w * 6 + nt0;
        f32x4 acc = {0.f, 0.f, 0.f, 0.f};
        const bf16x8* bp = (const bf16x8*)(Pq + (size_t)nt * 4 * 512);
        #pragma unroll
        for (int kt = 0; kt < 4; kt++) {
            bf16x8 bfr = bp[kt * 64 + lane];
            acc = __builtin_amdgcn_mfma_f32_16x16x32_bf16(a1[kt], bfr, acc, 0, 0, 0);
        }
        int n = nt * 16 + m;
        int h = n / 96, mm = (n % 96) / 32, d = n % 32;
        float qbv = qb[h * 32 + d], vbv = vb[h * 32 + d];
        #pragma unroll
        for (int r = 0; r < 4; r++) {
            int row = row0 + quad * 4 + r;
            int bb = row / Sq, s = row % Sq;
            int bh = bb * NH + h;
            size_t idx = (((size_t)bh) * Sq + s) * 32 + d;
            float a = acc[r];
            if (mm == 0) {
                float qv = (a + qbv) * inv_scale;
                q[idx] = qv;
                qbf[((size_t)bh * SP + s) * 32 + d] = __float2bfloat16(qv);
            } else if (mm == 1) {
                k[idx] = a;
                kbf[((size_t)bh * SP + s) * 32 + d] = __float2bfloat16(a);
            } else {
                vT[((size_t)bh * 32 + d) * SP + s] = __float2bfloat16(a + vbv);
            }
        }
    }
}

// -------- positional projections, ALL layers at once: posk/posq [L][16][128] --------
__global__ void pos_kernel(const float* __restrict__ rel_emb,
                           const float* __restrict__ pkW_all, const float* __restrict__ pqW_all,
                           const float* __restrict__ pqb_all,
                           float* __restrict__ posk, float* __restrict__ posq) {
    int l = blockIdx.y;         // 0..NL-1
    int bi = blockIdx.x;        // 0..31
    int which = bi >> 4;        // 0: posk, 1: posq
    int r = bi & 15;
    int t = threadIdx.x;        // 0..127
    __shared__ float re[128];
    re[t] = rel_emb[r * 128 + t];
    __syncthreads();
    const float* W = (which ? pqW_all : pkW_all) + (size_t)l * 128 * 128;
    float a = 0.0f;
    for (int k = 0; k < 128; k++) a += re[k] * W[k * 128 + t];
    if (which) { a = (a + pqb_all[l * 128 + t]) * 0.10206207261596576f; posq[(size_t)l * 2048 + r * 128 + t] = a; }
    else       { posk[(size_t)l * 2048 + r * 128 + t] = a; }
}

// -------- c2p[b,h,s,16] = q . posk[h,r]; p2c[b,h,s,16] = k . posq[h,r] --------
__global__ void relscore_kernel(const float* q, const float* k,
                                const float* posk, const float* posq,
                                float* c2p, float* p2c) {
    int bh = blockIdx.x;       // 0..255
    int chunk = blockIdx.y;    // 0..4
    int h = bh % NH;
    int t = threadIdx.x;       // 0..255
    __shared__ float pk[16 * 32];
    __shared__ float pq[16 * 32];
    for (int i = t; i < 512; i += 256) {
        int r = i / 32, d = i % 32;
        pk[i] = posk[r * 128 + h * 32 + d];
        pq[i] = posq[r * 128 + h * 32 + d];
    }
    __syncthreads();
    int sbase = chunk * 60;
    const float* qb = q + (size_t)bh * Sq * 32;
    const float* kb = k + (size_t)bh * Sq * 32;
    float* c2pb = c2p + (size_t)bh * Sq * 16;
    float* p2cb = p2c + (size_t)bh * Sq * 16;
    for (int idx = t; idx < 2 * 60 * 16; idx += 256) {
        int sel = idx / (60 * 16);
        int rem = idx % (60 * 16);
        int s = sbase + rem / 16, r = rem % 16;
        const float* src = sel ? (kb + s * 32) : (qb + s * 32);
        const float* pp  = sel ? (pq + r * 32) : (pk + r * 32);
        float a = 0.0f;
        for (int d = 0; d < 32; d++) a += src[d] * pp[d];
        if (sel) p2cb[s * 16 + r] = a; else c2pb[s * 16 + r] = a;
    }
}

// -------- MFMA attention (R14 win, unchanged) --------
__global__ __launch_bounds__(256) void attn_mfma_kernel(const __hip_bfloat16* __restrict__ qbf,
                                                        const __hip_bfloat16* __restrict__ kbf,
                                                        const __hip_bfloat16* __restrict__ vT,
                                                        const float* __restrict__ c2p, const float* __restrict__ p2c,
                                                        const float* __restrict__ mask, float* __restrict__ ctx) {
    int bh = blockIdx.x;            // 0..255
    int b = bh >> 2, h = bh & 3;
    int t = threadIdx.x;
    int w = t >> 6, lane = t & 63;
    int m = lane & 15, quad = lane >> 4;

    __shared__ float p2cS[SP * 17];                       // 20672 B, block-shared
    __shared__ float c2pS[4][16 * 17];                    // per-wave
    __shared__ __align__(16) __hip_bfloat16 pT[4][16 * 40]; // per-wave, stride 40

    for (int i = t; i < SP * 16; i += 256) {
        int j = i >> 4, c = i & 15;
        p2cS[j * 17 + c] = (j < Sq) ? p2c[((size_t)bh * Sq + j) * 16 + c] : 0.0f;
    }
    __syncthreads();

    int qt = blockIdx.y * 4 + w;    // 0..19
    if (qt >= 19) return;           // no barriers after this point
    int q0 = qt * 16;

    float* c2pW = c2pS[w];
    __hip_bfloat16* pTW = pT[w];
    #pragma unroll
    for (int it = 0; it < 4; it++) {
        int i = lane + it * 64;
        int row = i >> 4, c = i & 15;
        int qi = q0 + row;
        c2pW[row * 17 + c] = (qi < Sq) ? c2p[((size_t)bh * Sq + qi) * 16 + c] : 0.0f;
    }

    bf16x8 aq = *(const bf16x8*)&qbf[((size_t)bh * SP + q0 + m) * 32 + quad * 8];

    float qmv[4];
    #pragma unroll
    for (int r = 0; r < 4; r++) {
        int qi = q0 + quad * 4 + r;
        qmv[r] = (qi < Sq) ? mask[b * Sq + qi] : 0.0f;
    }

    f32x4 oacc[2] = {{0.f,0.f,0.f,0.f}, {0.f,0.f,0.f,0.f}};
    float l_r[4] = {0.f, 0.f, 0.f, 0.f};

    for (int jt2 = 0; jt2 < 10; jt2++) {
        int j0 = jt2 * 32;
        #pragma unroll
        for (int half = 0; half < 2; half++) {
            int j = j0 + half * 16 + m;
            bf16x8 kf = *(const bf16x8*)&kbf[((size_t)bh * SP + j) * 32 + quad * 8];
            f32x4 sc = __builtin_amdgcn_mfma_f32_16x16x32_bf16(aq, kf, (f32x4){0.f,0.f,0.f,0.f}, 0, 0, 0);
            float jmv = (j < Sq) ? mask[b * Sq + j] : 0.0f;
            #pragma unroll
            for (int r = 0; r < 4; r++) {
                int row = quad * 4 + r;
                int qi = q0 + row;
                int rr = qi - j + 8; rr = rr < 0 ? 0 : (rr > 15 ? 15 : rr);
                float sv = sc[r] + c2pW[row * 17 + rr] + p2cS[j * 17 + rr];
                float p = (jmv * qmv[r] > 0.0f) ? __expf(sv) : 0.0f;
                l_r[r] += p;
                pTW[row * 40 + half * 16 + m] = __float2bfloat16(p);
            }
        }
        bf16x8 ap = *(bf16x8*)&pTW[m * 40 + quad * 8];
        #pragma unroll
        for (int nt = 0; nt < 2; nt++) {
            bf16x8 vf = *(const bf16x8*)&vT[((size_t)bh * 32 + nt * 16 + m) * SP + j0 + quad * 8];
            oacc[nt] = __builtin_amdgcn_mfma_f32_16x16x32_bf16(ap, vf, oacc[nt], 0, 0, 0);
        }
    }

    #pragma unroll
    for (int r = 0; r < 4; r++) {
        float ls = l_r[r];
        ls += __shfl_xor(ls, 1); ls += __shfl_xor(ls, 2);
        ls += __shfl_xor(ls, 4); ls += __shfl_xor(ls, 8);
        float inv = (qmv[r] > 0.0f && ls > 0.0f) ? 1.0f / ls : 0.0f;
        int qi = q0 + quad * 4 + r;
        if (qi < Sq) {
            size_t base = ((size_t)(b * Sq + qi)) * 128 + h * 32;
            ctx[base + m]      = oacc[0][r] * inv;
            ctx[base + 16 + m] = oacc[1][r] * inv;
        }
    }
}

// -------- attn_out via MFMA: 16 rows/block, N=128 + residual + LN --------
__global__ __launch_bounds__(256) void attnout_mfma_kernel(const float* __restrict__ ctx,
                                                           const __hip_bfloat16* __restrict__ Po,
                                                           const float* __restrict__ bias,
                                                           const float* __restrict__ ln_s, const float* __restrict__ ln_b,
                                                           float* __restrict__ x) {
    int blk = blockIdx.x;       // 0..1199
    int t = threadIdx.x;        // 0..255
    int w = t >> 6, lane = t & 63;
    int row0 = blk * 16;
    __shared__ __align__(16) __hip_bfloat16 ca[16 * 136];
    __shared__ float xr[16 * 128];
    __shared__ float dbuf[16 * 132];
    for (int i = t; i < 512; i += 256) {
        float4 cv4 = ((const float4*)(ctx + (size_t)row0 * 128))[i];
        float4 xv4 = ((const float4*)(x + (size_t)row0 * 128))[i];
        int r = i >> 5, c4 = (i & 31) * 4;
        *(float4*)&xr[r * 128 + c4] = xv4;
        __hip_bfloat16* d = &ca[r * 136 + c4];
        d[0] = __float2bfloat16(cv4.x); d[1] = __float2bfloat16(cv4.y);
        d[2] = __float2bfloat16(cv4.z); d[3] = __float2bfloat16(cv4.w);
    }
    __syncthreads();
    int m = lane & 15, quad = lane >> 4;
    bf16x8 a1[4];
    #pragma unroll
    for (int kt = 0; kt < 4; kt++) a1[kt] = *(bf16x8*)&ca[m * 136 + kt * 32 + quad * 8];
    f32x4 acc2[2] = {{0.f,0.f,0.f,0.f}, {0.f,0.f,0.f,0.f}};
    #pragma unroll
    for (int kt = 0; kt < 4; kt++) {
        #pragma unroll
        for (int nt0 = 0; nt0 < 2; nt0++) {
            int nt = w * 2 + nt0;
            bf16x8 bfr = ((const bf16x8*)(Po + (size_t)nt * 4 * 512))[kt * 64 + lane];
            acc2[nt0] = __builtin_amdgcn_mfma_f32_16x16x32_bf16(a1[kt], bfr, acc2[nt0], 0, 0, 0);
        }
    }
    #pragma unroll
    for (int nt0 = 0; nt0 < 2; nt0++) {
        int n = (w * 2 + nt0) * 16 + m;
        #pragma unroll
        for (int r = 0; r < 4; r++) dbuf[(quad * 4 + r) * 132 + n] = acc2[nt0][r];
    }
    __syncthreads();
    #pragma unroll
    for (int rr = 0; rr < 4; rr++) {
        int row = w * 4 + rr;
        int c0 = lane, c1 = lane + 64;
        float y0 = dbuf[row * 132 + c0] + bias[c0] + xr[row * 128 + c0];
        float y1 = dbuf[row * 132 + c1] + bias[c1] + xr[row * 128 + c1];
        float sm = y0 + y1;
        #pragma unroll
        for (int o = 32; o > 0; o >>= 1) sm += __shfl_xor(sm, o);
        float mu = sm * (1.0f / 128.0f);
        float d0 = y0 - mu, d1 = y1 - mu;
        float vv = d0 * d0 + d1 * d1;
        #pragma unroll
        for (int o = 32; o > 0; o >>= 1) vv += __shfl_xor(vv, o);
        float rstd = rsqrtf(vv * (1.0f / 128.0f) + 1e-7f);
        x[(size_t)(row0 + row) * 128 + c0] = d0 * rstd * ln_s[c0] + ln_b[c0];
        x[(size_t)(row0 + row) * 128 + c1] = d1 * rstd * ln_s[c1] + ln_b[c1];
    }
}

// -------- fused FFN via MFMA: 16 rows/block (R12 win, unchanged) --------
__global__ __launch_bounds__(256) void ffn_mfma_kernel(const float* __restrict__ x,
                                                       const __hip_bfloat16* __restrict__ P1,
                                                       const float* __restrict__ b1,
                                                       const __hip_bfloat16* __restrict__ P2,
                                                       const float* __restrict__ b2,
                                                       const float* __restrict__ ln_s, const float* __restrict__ ln_b,
                                                       float* __restrict__ xout) {
    int blk = blockIdx.x;       // 0..1199
    int t = threadIdx.x;        // 0..255
    int w = t >> 6, lane = t & 63;
    int row0 = blk * 16;

    __shared__ __align__(16) __hip_bfloat16 xa[16 * 136];
    __shared__ float xr[16 * 128];
    __shared__ __align__(16) __hip_bfloat16 ha[16 * 520];
    __shared__ float dbuf[16 * 132];

    for (int i = t; i < 512; i += 256) {
        float4 v4 = ((const float4*)(x + (size_t)row0 * 128))[i];
        int r = i >> 5, c4 = (i & 31) * 4;
        *(float4*)&xr[r * 128 + c4] = v4;
        __hip_bfloat16* d = &xa[r * 136 + c4];
        d[0] = __float2bfloat16(v4.x); d[1] = __float2bfloat16(v4.y);
        d[2] = __float2bfloat16(v4.z); d[3] = __float2bfloat16(v4.w);
    }
    __syncthreads();

    int m = lane & 15, quad = lane >> 4;

    bf16x8 a1[4];
    #pragma unroll
    for (int kt = 0; kt < 4; kt++)
        a1[kt] = *(bf16x8*)&xa[m * 136 + kt * 32 + quad * 8];
    #pragma unroll
    for (int nt0 = 0; nt0 < 8; nt0++) {
        int nt = w * 8 + nt0;
        f32x4 acc = {0.f, 0.f, 0.f, 0.f};
        const bf16x8* bp = (const bf16x8*)(P1 + (size_t)nt * 4 * 512);
        #pragma unroll
        for (int kt = 0; kt < 4; kt++) {
            bf16x8 bfr = bp[kt * 64 + lane];
            acc = __builtin_amdgcn_mfma_f32_16x16x32_bf16(a1[kt], bfr, acc, 0, 0, 0);
        }
        int n = nt * 16 + m;
        float bb = b1[n];
        #pragma unroll
        for (int r = 0; r < 4; r++)
            ha[(quad * 4 + r) * 520 + n] = __float2bfloat16(gelu_f(acc[r] + bb));
    }
    __syncthreads();

    f32x4 acc2[2] = {{0.f,0.f,0.f,0.f}, {0.f,0.f,0.f,0.f}};
    #pragma unroll
    for (int kt = 0; kt < 16; kt++) {
        bf16x8 a = *(bf16x8*)&ha[m * 520 + kt * 32 + quad * 8];
        #pragma unroll
        for (int nt0 = 0; nt0 < 2; nt0++) {
            int nt = w * 2 + nt0;
            bf16x8 bfr = ((const bf16x8*)(P2 + (size_t)nt * 16 * 512))[kt * 64 + lane];
            acc2[nt0] = __builtin_amdgcn_mfma_f32_16x16x32_bf16(a, bfr, acc2[nt0], 0, 0, 0);
        }
    }
    #pragma unroll
    for (int nt0 = 0; nt0 < 2; nt0++) {
        int n = (w * 2 + nt0) * 16 + m;
        #pragma unroll
        for (int r = 0; r < 4; r++)
            dbuf[(quad * 4 + r) * 132 + n] = acc2[nt0][r];
    }
    __syncthreads();

    #pragma unroll
    for (int rr = 0; rr < 4; rr++) {
        int row = w * 4 + rr;
        int c0 = lane, c1 = lane + 64;
        float y0 = dbuf[row * 132 + c0] + b2[c0] + xr[row * 128 + c0];
        float y1 = dbuf[row * 132 + c1] + b2[c1] + xr[row * 128 + c1];
        float sm = y0 + y1;
        #pragma unroll
        for (int o = 32; o > 0; o >>= 1) sm += __shfl_xor(sm, o);
        float mu = sm * (1.0f / 128.0f);
        float d0 = y0 - mu, d1 = y1 - mu;
        float vv = d0 * d0 + d1 * d1;
        #pragma unroll
        for (int o = 32; o > 0; o >>= 1) vv += __shfl_xor(vv, o);
        float rstd = rsqrtf(vv * (1.0f / 128.0f) + 1e-7f);
        xout[(size_t)(row0 + row) * 128 + c0] = d0 * rstd * ln_s[c0] + ln_b[c0];
        xout[(size_t)(row0 + row) * 128 + c1] = d1 * rstd * ln_s[c1] + ln_b[c1];
    }
}

// -------- reconstruction MLP via MFMA: 16 rows/block; 128->128->64->5 --------
__global__ __launch_bounds__(256) void rec_mfma_kernel(const float* __restrict__ x,
                                                       const __hip_bfloat16* __restrict__ Pr1,
                                                       const float* __restrict__ b1,
                                                       const __hip_bfloat16* __restrict__ Pr2,
                                                       const float* __restrict__ b2,
                                                       const float* __restrict__ W3, const float* __restrict__ b3,
                                                       float* __restrict__ r3) {
    int blk = blockIdx.x;       // 0..1199
    int t = threadIdx.x;        // 0..255
    int w = t >> 6, lane = t & 63;
    int row0 = blk * 16;
    __shared__ __align__(16) __hip_bfloat16 xa[16 * 136];
    __shared__ __align__(16) __hip_bfloat16 ha[16 * 136];  // r1 bf16, A-layout staging
    __shared__ float r2s[16 * 68];                          // r2 fp32
    for (int i = t; i < 512; i += 256) {
        float4 v4 = ((const float4*)(x + (size_t)row0 * 128))[i];
        int r = i >> 5, c4 = (i & 31) * 4;
        __hip_bfloat16* d = &xa[r * 136 + c4];
        d[0] = __float2bfloat16(v4.x); d[1] = __float2bfloat16(v4.y);
        d[2] = __float2bfloat16(v4.z); d[3] = __float2bfloat16(v4.w);
    }
    __syncthreads();
    int m = lane & 15, quad = lane >> 4;

    // phase 1: r1 = gelu(x @ W1 + b1); N=128, 2 n-tiles/wave
    bf16x8 a1[4];
    #pragma unroll
    for (int kt = 0; kt < 4; kt++) a1[kt] = *(bf16x8*)&xa[m * 136 + kt * 32 + quad * 8];
    #pragma unroll
    for (int nt0 = 0; nt0 < 2; nt0++) {
        int nt = w * 2 + nt0;
        f32x4 acc = {0.f, 0.f, 0.f, 0.f};
        const bf16x8* bp = (const bf16x8*)(Pr1 + (size_t)nt * 4 * 512);
        #pragma unroll
        for (int kt = 0; kt < 4; kt++) {
            bf16x8 bfr = bp[kt * 64 + lane];
            acc = __builtin_amdgcn_mfma_f32_16x16x32_bf16(a1[kt], bfr, acc, 0, 0, 0);
        }
        int n = nt * 16 + m;
        float bb = b1[n];
        #pragma unroll
        for (int r = 0; r < 4; r++)
            ha[(quad * 4 + r) * 136 + n] = __float2bfloat16(gelu_f(acc[r] + bb));
    }
    __syncthreads();

    // phase 2: r2 = gelu(r1 @ W2 + b2); N=64, 1 n-tile/wave
    {
        f32x4 acc = {0.f, 0.f, 0.f, 0.f};
        const bf16x8* bp = (const bf16x8*)(Pr2 + (size_t)w * 4 * 512);
        #pragma unroll
        for (int kt = 0; kt < 4; kt++) {
            bf16x8 a = *(bf16x8*)&ha[m * 136 + kt * 32 + quad * 8];
            bf16x8 bfr = bp[kt * 64 + lane];
            acc = __builtin_amdgcn_mfma_f32_16x16x32_bf16(a, bfr, acc, 0, 0, 0);
        }
        int n = w * 16 + m;
        float bb = b2[n];
        #pragma unroll
        for (int r = 0; r < 4; r++)
            r2s[(quad * 4 + r) * 68 + n] = gelu_f(acc[r] + bb);
    }
    __syncthreads();

    // phase 3: r3 = gelu(r2 @ W3 + b3); [16 rows x 5 cols], VALU
    if (t < 80) {
        int row = t / 5, c = t % 5;
        float a = b3[c];
        for (int k = 0; k < 64; k++) a += r2s[row * 68 + k] * W3[k * 5 + c];
        r3[(size_t)(row0 + row) * 5 + c] = gelu_f(a);
    }
}

// -------- connection head v2 (R15 win, unchanged) --------
__global__ void conn_kernel(const float* __restrict__ r3, const float* __restrict__ W,
                            const float* __restrict__ b, void* out, const unsigned* maskw) {
    bool bfm = bf16_mode(maskw);
    int cb = blockIdx.x;     // 0..39
    int bg = blockIdx.y;     // 0..15
    int t = threadIdx.x;     // 0..255
    int cl = t & 63;
    int kq = t >> 6;
    int col = cb * 64 + cl;
    __shared__ float rs[4 * 1500];
    __shared__ float pacc[4 * 64 * 4];
    {
        const float4* src = (const float4*)(r3 + (size_t)bg * 4 * 1500);
        for (int i = t; i < 1500; i += 256) ((float4*)rs)[i] = src[i];
    }
    __syncthreads();
    float acc[4] = {0.f, 0.f, 0.f, 0.f};
    if (col < 2500) {
        for (int k = kq * 4; k < 1500; k += 16) {
            float w0 = W[(size_t)(k + 0) * 2500 + col];
            float w1 = W[(size_t)(k + 1) * 2500 + col];
            float w2 = W[(size_t)(k + 2) * 2500 + col];
            float w3 = W[(size_t)(k + 3) * 2500 + col];
            #pragma unroll
            for (int bb = 0; bb < 4; bb++) {
                float4 rv = *(const float4*)&rs[bb * 1500 + k];
                acc[bb] += rv.x * w0 + rv.y * w1 + rv.z * w2 + rv.w * w3;
            }
        }
    }
    #pragma unroll
    for (int bb = 0; bb < 4; bb++) pacc[(kq * 64 + cl) * 4 + bb] = acc[bb];
    __syncthreads();
    if (kq == 0 && col < 2500) {
        float bv = b[col];
        #pragma unroll
        for (int bb = 0; bb < 4; bb++) {
            float a = bv + pacc[(0 * 64 + cl) * 4 + bb] + pacc[(1 * 64 + cl) * 4 + bb]
                         + pacc[(2 * 64 + cl) * 4 + bb] + pacc[(3 * 64 + cl) * 4 + bb];
            int ob = bg * 4 + bb;
            if (bfm) ((__hip_bfloat16*)out)[(size_t)ob * 2500 + col] = __float2bfloat16(a);
            else     ((float*)out)[(size_t)ob * 2500 + col] = a;
        }
    }
}

extern "C" void kernel_launch(void* const* d_in, const int* in_sizes, int n_in,
                              void* d_out, int out_size, void* d_ws, size_t ws_size,
                              hipStream_t stream) {
    float* ws = (float*)d_ws;

    float* cv[NIN];
    size_t off = 0;
    for (int i = 0; i < NIN; i++) { cv[i] = ws + off; off += (size_t)in_sizes[i]; }

    const float* inp      = cv[0];
    const float* mask     = cv[1];
    const float* emb_W1   = cv[2];
    const float* emb_b1   = cv[3];
    const float* emb_W2   = cv[4];
    const float* emb_b2   = cv[5];
    const float* emb_W3   = cv[6];
    const float* emb_b3   = cv[7];
    const float* tok_emb  = cv[8];
    const float* emb_ln_s = cv[9];
    const float* emb_ln_b = cv[10];
    const float* rel_emb  = cv[11];
    const float* qkv_W    = cv[12];
    const float* q_bias   = cv[13];
    const float* v_bias   = cv[14];
    const float* pos_k_W  = cv[15];
    const float* pos_q_W  = cv[16];
    const float* pos_q_b  = cv[17];
    const float* attn_out_W = cv[18];
    const float* attn_out_b = cv[19];
    const float* ln1_s    = cv[20];
    const float* ln1_b    = cv[21];
    const float* ffn_W1   = cv[22];
    const float* ffn_b1   = cv[23];
    const float* ffn_W2   = cv[24];
    const float* ffn_b2   = cv[25];
    const float* ln2_s    = cv[26];
    const float* ln2_b    = cv[27];
    const float* rec_W1   = cv[28];
    const float* rec_b1   = cv[29];
    const float* rec_W2   = cv[30];
    const float* rec_b2   = cv[31];
    const float* rec_W3   = cv[32];
    const float* rec_b3   = cv[33];
    const float* conn_W   = cv[34];
    const float* conn_b   = cv[35];

    const int NTOK = Bq * Sq;            // 19200
    float* x    = ws + off;
    float* q    = x    + (size_t)NTOK * 128;
    float* k    = q    + (size_t)Bq * NH * Sq * 32;
    float* ctx  = k    + (size_t)Bq * NH * Sq * 32;
    float* c2p  = ctx  + (size_t)NTOK * 128;
    float* p2c  = c2p  + (size_t)Bq * NH * Sq * 16;
    float* posk = p2c  + (size_t)Bq * NH * Sq * 16;      // [NL][16][128]
    float* posq = posk + (size_t)NL * 16 * 128;
    float* r3b  = posq + (size_t)NL * 16 * 128;
    float* endf = r3b  + (size_t)NTOK * 5;
    __hip_bfloat16* P1 = (__hip_bfloat16*)endf;          // 8 x 65536 bf16
    __hip_bfloat16* P2 = P1 + (size_t)NL * 65536;
    __hip_bfloat16* Pq = P2 + (size_t)NL * 65536;        // 8 x 49152
    __hip_bfloat16* Po = Pq + (size_t)NL * 49152;        // 8 x 16384
    __hip_bfloat16* qbf = Po + (size_t)NL * 16384;       // 256*SP*32 each
    __hip_bfloat16* kbf = qbf + (size_t)256 * SP * 32;
    __hip_bfloat16* vTb = kbf + (size_t)256 * SP * 32;
    __hip_bfloat16* Pr1 = vTb + (size_t)256 * SP * 32;   // 16384
    __hip_bfloat16* Pr2 = Pr1 + 16384;                   // 8192

    const unsigned* maskw = (const unsigned*)d_in[1];

    ConvArgs ca;
    for (int i = 0; i < NIN; i++) {
        ca.src[i] = d_in[i];
        ca.dst[i] = cv[i];
        ca.n[i] = in_sizes[i];
    }
    convert_kernel<<<dim3(256, NIN), 256, 0, stream>>>(ca, maskw);
    pack_kernel<<<dim3(32, NL, 6), 256, 0, stream>>>(ffn_W1, ffn_W2, qkv_W, attn_out_W,
                                                     rec_W1, rec_W2,
                                                     P1, P2, Pq, Po, Pr1, Pr2);

    embed16_kernel<<<NTOK / 16, 256, 0, stream>>>(inp, mask, emb_W1, emb_b1, emb_W2, emb_b2,
                                                  emb_W3, emb_b3, tok_emb, emb_ln_s, emb_ln_b, x);

    // all-layer positional projections (hoisted out of the layer loop)
    pos_kernel<<<dim3(32, NL), 128, 0, stream>>>(rel_emb, pos_k_W, pos_q_W, pos_q_b, posk, posq);

    for (int l = 0; l < NL; l++) {
        qkv_mfma_kernel<<<NTOK / 16, 256, 0, stream>>>(x, Pq + (size_t)l * 49152,
                                                       q_bias + l * 128, v_bias + l * 128,
                                                       q, k, qbf, kbf, vTb);
        relscore_kernel<<<dim3(Bq * NH, 5), 256, 0, stream>>>(q, k, posk + (size_t)l * 2048,
                                                              posq + (size_t)l * 2048, c2p, p2c);
        attn_mfma_kernel<<<dim3(256, 5), 256, 0, stream>>>(qbf, kbf, vTb, c2p, p2c, mask, ctx);
        attnout_mfma_kernel<<<NTOK / 16, 256, 0, stream>>>(ctx, Po + (size_t)l * 16384,
                                                           attn_out_b + l * 128,
                                                           ln1_s + l * 128, ln1_b + l * 128, x);
        ffn_mfma_kernel<<<NTOK / 16, 256, 0, stream>>>(x, P1 + (size_t)l * 65536, ffn_b1 + l * 512,
                                                       P2 + (size_t)l * 65536, ffn_b2 + l * 128,
                                                       ln2_s + l * 128, ln2_b + l * 128, x);
    }

    rec_mfma_kernel<<<NTOK / 16, 256, 0, stream>>>(x, Pr1, rec_b1, Pr2, rec_b2,
                                                   rec_W3, rec_b3, r3b);
    conn_kernel<<<dim3(40, 16), 256, 0, stream>>>(r3b, conn_W, conn_b, d_out, maskw);
}

// Round 3
// 1152.807 us; speedup vs baseline: 1.0689x; 1.0446x over previous
//
#include <hip/hip_runtime.h>
#include <hip/hip_bf16.h>
#include <math.h>

#define Bq 64
#define Sq 300
#define NH 4
#define DHd 32
#define Dd 128
#define NL 8
#define FF 512
#define NIN 36
#define SP 304   // padded seq for MFMA tiles

typedef __attribute__((ext_vector_type(8))) short bf16x8;
typedef __attribute__((ext_vector_type(4))) float f32x4;

__device__ __forceinline__ float gelu_f(float x) {
    return 0.5f * x * (1.0f + erff(x * 0.70710678118654752f));
}
__device__ __forceinline__ bool bf16_mode(const unsigned* maskw) {
    return maskw[0] == 0x3F803F80u;   // two bf16 1.0s; f32 1.0 is 0x3F800000
}

// -------- dtype-agnostic input widening: all 36 inputs -> fp32 shadow in ws --------
struct ConvArgs {
    const void* src[NIN];
    float* dst[NIN];
    int n[NIN];
};

__global__ void convert_kernel(ConvArgs a, const unsigned* maskw) {
    bool bfm = bf16_mode(maskw);
    int bi = blockIdx.y;
    int n = a.n[bi];
    float* dst = a.dst[bi];
    int stride = gridDim.x * blockDim.x;
    int i0 = blockIdx.x * blockDim.x + threadIdx.x;
    if (bfm) {
        const __hip_bfloat16* s = (const __hip_bfloat16*)a.src[bi];
        for (int i = i0; i < n; i += stride) dst[i] = __bfloat162float(s[i]);
    } else {
        const float* s = (const float*)a.src[bi];
        for (int i = i0; i < n; i += stride) dst[i] = s[i];
    }
}

// -------- pack weights to MFMA B-operand layout [nt][kt][64][8] bf16 --------
// which: 0=ffn_W1(K128,N512) 1=ffn_W2(K512,N128) 2=qkv_W(K128,N384)
//        3=attn_out_W(K128,N128) 4=rec_W1(K128,N128,l=0) 5=rec_W2(K128,N64,l=0)
//        6=emb_W2(K64,N128,l=0) 7=emb_W3(K128,N128,l=0)
__global__ void pack_kernel(const float* __restrict__ W1all, const float* __restrict__ W2all,
                            const float* __restrict__ Wqall, const float* __restrict__ Woall,
                            const float* __restrict__ Wr1, const float* __restrict__ Wr2,
                            const float* __restrict__ We2, const float* __restrict__ We3,
                            __hip_bfloat16* __restrict__ P1, __hip_bfloat16* __restrict__ P2,
                            __hip_bfloat16* __restrict__ Pq, __hip_bfloat16* __restrict__ Po,
                            __hip_bfloat16* __restrict__ Pr1, __hip_bfloat16* __restrict__ Pr2,
                            __hip_bfloat16* __restrict__ Pe2, __hip_bfloat16* __restrict__ Pe3) {
    int l = blockIdx.y;
    int which = blockIdx.z;
    if (which >= 4 && l != 0) return;
    int K = (which == 1) ? 512 : ((which == 6) ? 64 : 128);
    int N = (which == 0) ? 512 : (which == 1 ? 128 : (which == 2 ? 384 : (which == 5 ? 64 : 128)));
    int slots = (K / 32) * (N / 16) * 64;
    int idx = blockIdx.x * 256 + threadIdx.x;
    if (idx >= slots) return;
    int lane = idx & 63;
    int nkt = K / 32;
    int kt = (idx >> 6) % nkt;
    int nt = (idx >> 6) / nkt;
    const float* W; __hip_bfloat16* P;
    switch (which) {
        case 0:  W = W1all + (size_t)l * 128 * 512; P = P1 + (size_t)l * 65536; break;
        case 1:  W = W2all + (size_t)l * 512 * 128; P = P2 + (size_t)l * 65536; break;
        case 2:  W = Wqall + (size_t)l * 128 * 384; P = Pq + (size_t)l * 49152; break;
        case 3:  W = Woall + (size_t)l * 128 * 128; P = Po + (size_t)l * 16384; break;
        case 4:  W = Wr1; P = Pr1; break;
        case 5:  W = Wr2; P = Pr2; break;
        case 6:  W = We2; P = Pe2; break;
        default: W = We3; P = Pe3; break;
    }
    P += (size_t)idx * 8;
    int n = nt * 16 + (lane & 15);
    int k0 = kt * 32 + (lane >> 4) * 8;
    #pragma unroll
    for (int j = 0; j < 8; j++) P[j] = __float2bfloat16(W[(size_t)(k0 + j) * N + n]);
}

// -------- embedding v3: MFMA for layers 2&3 (attnout-style), fp32 layer1 --------
// MLP(3->64->128->128) + tok_emb + LN + mask; 16 rows/block.
__global__ __launch_bounds__(256) void embed_mfma_kernel(
        const float* __restrict__ inp, const float* __restrict__ mask,
        const float* __restrict__ W1, const float* __restrict__ b1,
        const __hip_bfloat16* __restrict__ Pe2, const float* __restrict__ b2,
        const __hip_bfloat16* __restrict__ Pe3, const float* __restrict__ b3,
        const float* __restrict__ tok_emb,
        const float* __restrict__ ln_s, const float* __restrict__ ln_b,
        float* __restrict__ x) {
    int blk = blockIdx.x;       // 0..1199
    int t = threadIdx.x;        // 0..255
    int w = t >> 6, lane = t & 63;
    int row0 = blk * 16;
    __shared__ float f[16][4];
    __shared__ __align__(16) __hip_bfloat16 e1a[16 * 72];   // layer1 out, A-layout
    __shared__ __align__(16) __hip_bfloat16 e2a[16 * 136];  // layer2 out, A-layout
    __shared__ float dbuf[16 * 132];
    if (t < 64) f[t >> 2][t & 3] = inp[(size_t)(row0 + (t >> 2)) * 4 + (t & 3)];
    __syncthreads();
    {   // layer1: 3->64 fp32, 4 outputs/thread, emit bf16
        int r1 = t >> 4, n0 = (t & 15) * 4;
        float f0 = f[r1][0], f1 = f[r1][1], f2 = f[r1][2];
        #pragma unroll
        for (int j = 0; j < 4; j++) {
            int n = n0 + j;
            float a = b1[n] + f0 * W1[n] + f1 * W1[64 + n] + f2 * W1[128 + n];
            e1a[r1 * 72 + n] = __float2bfloat16(gelu_f(a));
        }
    }
    __syncthreads();
    int m = lane & 15, quad = lane >> 4;
    // layer2 MFMA: K=64 (2 kt), N=128 (2 nt/wave)
    bf16x8 a2[2];
    #pragma unroll
    for (int kt = 0; kt < 2; kt++) a2[kt] = *(bf16x8*)&e1a[m * 72 + kt * 32 + quad * 8];
    #pragma unroll
    for (int nt0 = 0; nt0 < 2; nt0++) {
        int nt = w * 2 + nt0;
        f32x4 acc = {0.f, 0.f, 0.f, 0.f};
        const bf16x8* bp = (const bf16x8*)(Pe2 + (size_t)nt * 2 * 512);
        #pragma unroll
        for (int kt = 0; kt < 2; kt++) {
            bf16x8 bfr = bp[kt * 64 + lane];
            acc = __builtin_amdgcn_mfma_f32_16x16x32_bf16(a2[kt], bfr, acc, 0, 0, 0);
        }
        int n = nt * 16 + m;
        float bb = b2[n];
        #pragma unroll
        for (int r = 0; r < 4; r++)
            e2a[(quad * 4 + r) * 136 + n] = __float2bfloat16(gelu_f(acc[r] + bb));
    }
    __syncthreads();
    // layer3 MFMA: K=128 (4 kt), N=128 (2 nt/wave); epilogue gelu + tok_emb
    bf16x8 a3[4];
    #pragma unroll
    for (int kt = 0; kt < 4; kt++) a3[kt] = *(bf16x8*)&e2a[m * 136 + kt * 32 + quad * 8];
    f32x4 acc2[2] = {{0.f,0.f,0.f,0.f}, {0.f,0.f,0.f,0.f}};
    #pragma unroll
    for (int kt = 0; kt < 4; kt++) {
        #pragma unroll
        for (int nt0 = 0; nt0 < 2; nt0++) {
            int nt = w * 2 + nt0;
            bf16x8 bfr = ((const bf16x8*)(Pe3 + (size_t)nt * 4 * 512))[kt * 64 + lane];
            acc2[nt0] = __builtin_amdgcn_mfma_f32_16x16x32_bf16(a3[kt], bfr, acc2[nt0], 0, 0, 0);
        }
    }
    #pragma unroll
    for (int nt0 = 0; nt0 < 2; nt0++) {
        int n = (w * 2 + nt0) * 16 + m;
        float bb = b3[n];
        #pragma unroll
        for (int r = 0; r < 4; r++) {
            int row = quad * 4 + r;
            int tok = (int)f[row][3];
            dbuf[row * 132 + n] = gelu_f(acc2[nt0][r] + bb) + tok_emb[tok * 128 + n];
        }
    }
    __syncthreads();
    // LN + mask epilogue (attnout pattern)
    #pragma unroll
    for (int rr = 0; rr < 4; rr++) {
        int row = w * 4 + rr;
        int c0 = lane, c1 = lane + 64;
        float y0 = dbuf[row * 132 + c0];
        float y1 = dbuf[row * 132 + c1];
        float sm = y0 + y1;
        #pragma unroll
        for (int o = 32; o > 0; o >>= 1) sm += __shfl_xor(sm, o);
        float mu = sm * (1.0f / 128.0f);
        float d0 = y0 - mu, d1 = y1 - mu;
        float vv = d0 * d0 + d1 * d1;
        #pragma unroll
        for (int o = 32; o > 0; o >>= 1) vv += __shfl_xor(vv, o);
        float rstd = rsqrtf(vv * (1.0f / 128.0f) + 1e-7f);
        float mk = mask[row0 + row];
        x[(size_t)(row0 + row) * 128 + c0] = (d0 * rstd * ln_s[c0] + ln_b[c0]) * mk;
        x[(size_t)(row0 + row) * 128 + c1] = (d1 * rstd * ln_s[c1] + ln_b[c1]) * mk;
    }
}

// -------- qkv via MFMA: also emits bf16 q/k [bh][SP][32] and vT [bh][32][SP] --------
__global__ __launch_bounds__(256) void qkv_mfma_kernel(const float* __restrict__ x,
                                                       const __hip_bfloat16* __restrict__ Pq,
                                                       const float* __restrict__ qb, const float* __restrict__ vb,
                                                       float* __restrict__ q, float* __restrict__ k,
                                                       __hip_bfloat16* __restrict__ qbf,
                                                       __hip_bfloat16* __restrict__ kbf,
                                                       __hip_bfloat16* __restrict__ vT) {
    int blk = blockIdx.x;       // 0..1199
    int t = threadIdx.x;        // 0..255
    int w = t >> 6, lane = t & 63;
    int row0 = blk * 16;
    __shared__ __align__(16) __hip_bfloat16 xa[16 * 136];
    for (int i = t; i < 512; i += 256) {
        float4 v4 = ((const float4*)(x + (size_t)row0 * 128))[i];
        int r = i >> 5, c4 = (i & 31) * 4;
        __hip_bfloat16* d = &xa[r * 136 + c4];
        d[0] = __float2bfloat16(v4.x); d[1] = __float2bfloat16(v4.y);
        d[2] = __float2bfloat16(v4.z); d[3] = __float2bfloat16(v4.w);
    }
    __syncthreads();
    int m = lane & 15, quad = lane >> 4;
    bf16x8 a1[4];
    #pragma unroll
    for (int kt = 0; kt < 4; kt++) a1[kt] = *(bf16x8*)&xa[m * 136 + kt * 32 + quad * 8];
    const float inv_scale = 0.10206207261596576f;  // 1/sqrt(96)
    #pragma unroll
    for (int nt0 = 0; nt0 < 6; nt0++) {
        int nt = w * 6 + nt0;
        f32x4 acc = {0.f, 0.f, 0.f, 0.f};
        const bf16x8* bp = (const bf16x8*)(Pq + (size_t)nt * 4 * 512);
        #pragma unroll
        for (int kt = 0; kt < 4; kt++) {
            bf16x8 bfr = bp[kt * 64 + lane];
            acc = __builtin_amdgcn_mfma_f32_16x16x32_bf16(a1[kt], bfr, acc, 0, 0, 0);
        }
        int n = nt * 16 + m;
        int h = n / 96, mm = (n % 96) / 32, d = n % 32;
        float qbv = qb[h * 32 + d], vbv = vb[h * 32 + d];
        #pragma unroll
        for (int r = 0; r < 4; r++) {
            int row = row0 + quad * 4 + r;
            int bb = row / Sq, s = row % Sq;
            int bh = bb * NH + h;
            size_t idx = (((size_t)bh) * Sq + s) * 32 + d;
            float a = acc[r];
            if (mm == 0) {
                float qv = (a + qbv) * inv_scale;
                q[idx] = qv;
                qbf[((size_t)bh * SP + s) * 32 + d] = __float2bfloat16(qv);
            } else if (mm == 1) {
                k[idx] = a;
                kbf[((size_t)bh * SP + s) * 32 + d] = __float2bfloat16(a);
            } else {
                vT[((size_t)bh * 32 + d) * SP + s] = __float2bfloat16(a + vbv);
            }
        }
    }
}

// -------- positional projections, ALL layers at once: posk/posq [L][16][128] --------
__global__ void pos_kernel(const float* __restrict__ rel_emb,
                           const float* __restrict__ pkW_all, const float* __restrict__ pqW_all,
                           const float* __restrict__ pqb_all,
                           float* __restrict__ posk, float* __restrict__ posq) {
    int l = blockIdx.y;         // 0..NL-1
    int bi = blockIdx.x;        // 0..31
    int which = bi >> 4;        // 0: posk, 1: posq
    int r = bi & 15;
    int t = threadIdx.x;        // 0..127
    __shared__ float re[128];
    re[t] = rel_emb[r * 128 + t];
    __syncthreads();
    const float* W = (which ? pqW_all : pkW_all) + (size_t)l * 128 * 128;
    float a = 0.0f;
    for (int k = 0; k < 128; k++) a += re[k] * W[k * 128 + t];
    if (which) { a = (a + pqb_all[l * 128 + t]) * 0.10206207261596576f; posq[(size_t)l * 2048 + r * 128 + t] = a; }
    else       { posk[(size_t)l * 2048 + r * 128 + t] = a; }
}

// -------- c2p[b,h,s,16] = q . posk[h,r]; p2c[b,h,s,16] = k . posq[h,r] --------
__global__ void relscore_kernel(const float* q, const float* k,
                                const float* posk, const float* posq,
                                float* c2p, float* p2c) {
    int bh = blockIdx.x;       // 0..255
    int chunk = blockIdx.y;    // 0..4
    int h = bh % NH;
    int t = threadIdx.x;       // 0..255
    __shared__ float pk[16 * 32];
    __shared__ float pq[16 * 32];
    for (int i = t; i < 512; i += 256) {
        int r = i / 32, d = i % 32;
        pk[i] = posk[r * 128 + h * 32 + d];
        pq[i] = posq[r * 128 + h * 32 + d];
    }
    __syncthreads();
    int sbase = chunk * 60;
    const float* qb = q + (size_t)bh * Sq * 32;
    const float* kb = k + (size_t)bh * Sq * 32;
    float* c2pb = c2p + (size_t)bh * Sq * 16;
    float* p2cb = p2c + (size_t)bh * Sq * 16;
    for (int idx = t; idx < 2 * 60 * 16; idx += 256) {
        int sel = idx / (60 * 16);
        int rem = idx % (60 * 16);
        int s = sbase + rem / 16, r = rem % 16;
        const float* src = sel ? (kb + s * 32) : (qb + s * 32);
        const float* pp  = sel ? (pq + r * 32) : (pk + r * 32);
        float a = 0.0f;
        for (int d = 0; d < 32; d++) a += src[d] * pp[d];
        if (sel) p2cb[s * 16 + r] = a; else c2pb[s * 16 + r] = a;
    }
}

// -------- MFMA attention (R14 win, unchanged) --------
__global__ __launch_bounds__(256) void attn_mfma_kernel(const __hip_bfloat16* __restrict__ qbf,
                                                        const __hip_bfloat16* __restrict__ kbf,
                                                        const __hip_bfloat16* __restrict__ vT,
                                                        const float* __restrict__ c2p, const float* __restrict__ p2c,
                                                        const float* __restrict__ mask, float* __restrict__ ctx) {
    int bh = blockIdx.x;            // 0..255
    int b = bh >> 2, h = bh & 3;
    int t = threadIdx.x;
    int w = t >> 6, lane = t & 63;
    int m = lane & 15, quad = lane >> 4;

    __shared__ float p2cS[SP * 17];                       // 20672 B, block-shared
    __shared__ float c2pS[4][16 * 17];                    // per-wave
    __shared__ __align__(16) __hip_bfloat16 pT[4][16 * 40]; // per-wave, stride 40

    for (int i = t; i < SP * 16; i += 256) {
        int j = i >> 4, c = i & 15;
        p2cS[j * 17 + c] = (j < Sq) ? p2c[((size_t)bh * Sq + j) * 16 + c] : 0.0f;
    }
    __syncthreads();

    int qt = blockIdx.y * 4 + w;    // 0..19
    if (qt >= 19) return;           // no barriers after this point
    int q0 = qt * 16;

    float* c2pW = c2pS[w];
    __hip_bfloat16* pTW = pT[w];
    #pragma unroll
    for (int it = 0; it < 4; it++) {
        int i = lane + it * 64;
        int row = i >> 4, c = i & 15;
        int qi = q0 + row;
        c2pW[row * 17 + c] = (qi < Sq) ? c2p[((size_t)bh * Sq + qi) * 16 + c] : 0.0f;
    }

    bf16x8 aq = *(const bf16x8*)&qbf[((size_t)bh * SP + q0 + m) * 32 + quad * 8];

    float qmv[4];
    #pragma unroll
    for (int r = 0; r < 4; r++) {
        int qi = q0 + quad * 4 + r;
        qmv[r] = (qi < Sq) ? mask[b * Sq + qi] : 0.0f;
    }

    f32x4 oacc[2] = {{0.f,0.f,0.f,0.f}, {0.f,0.f,0.f,0.f}};
    float l_r[4] = {0.f, 0.f, 0.f, 0.f};

    for (int jt2 = 0; jt2 < 10; jt2++) {
        int j0 = jt2 * 32;
        #pragma unroll
        for (int half = 0; half < 2; half++) {
            int j = j0 + half * 16 + m;
            bf16x8 kf = *(const bf16x8*)&kbf[((size_t)bh * SP + j) * 32 + quad * 8];
            f32x4 sc = __builtin_amdgcn_mfma_f32_16x16x32_bf16(aq, kf, (f32x4){0.f,0.f,0.f,0.f}, 0, 0, 0);
            float jmv = (j < Sq) ? mask[b * Sq + j] : 0.0f;
            #pragma unroll
            for (int r = 0; r < 4; r++) {
                int row = quad * 4 + r;
                int qi = q0 + row;
                int rr = qi - j + 8; rr = rr < 0 ? 0 : (rr > 15 ? 15 : rr);
                float sv = sc[r] + c2pW[row * 17 + rr] + p2cS[j * 17 + rr];
                float p = (jmv * qmv[r] > 0.0f) ? __expf(sv) : 0.0f;
                l_r[r] += p;
                pTW[row * 40 + half * 16 + m] = __float2bfloat16(p);
            }
        }
        bf16x8 ap = *(bf16x8*)&pTW[m * 40 + quad * 8];
        #pragma unroll
        for (int nt = 0; nt < 2; nt++) {
            bf16x8 vf = *(const bf16x8*)&vT[((size_t)bh * 32 + nt * 16 + m) * SP + j0 + quad * 8];
            oacc[nt] = __builtin_amdgcn_mfma_f32_16x16x32_bf16(ap, vf, oacc[nt], 0, 0, 0);
        }
    }

    #pragma unroll
    for (int r = 0; r < 4; r++) {
        float ls = l_r[r];
        ls += __shfl_xor(ls, 1); ls += __shfl_xor(ls, 2);
        ls += __shfl_xor(ls, 4); ls += __shfl_xor(ls, 8);
        float inv = (qmv[r] > 0.0f && ls > 0.0f) ? 1.0f / ls : 0.0f;
        int qi = q0 + quad * 4 + r;
        if (qi < Sq) {
            size_t base = ((size_t)(b * Sq + qi)) * 128 + h * 32;
            ctx[base + m]      = oacc[0][r] * inv;
            ctx[base + 16 + m] = oacc[1][r] * inv;
        }
    }
}

// -------- attn_out via MFMA: 16 rows/block, N=128 + residual + LN --------
__global__ __launch_bounds__(256) void attnout_mfma_kernel(const float* __restrict__ ctx,
                                                           const __hip_bfloat16* __restrict__ Po,
                                                           const float* __restrict__ bias,
                                                           const float* __restrict__ ln_s, const float* __restrict__ ln_b,
                                                           float* __restrict__ x) {
    int blk = blockIdx.x;       // 0..1199
    int t = threadIdx.x;        // 0..255
    int w = t >> 6, lane = t & 63;
    int row0 = blk * 16;
    __shared__ __align__(16) __hip_bfloat16 ca[16 * 136];
    __shared__ float xr[16 * 128];
    __shared__ float dbuf[16 * 132];
    for (int i = t; i < 512; i += 256) {
        float4 cv4 = ((const float4*)(ctx + (size_t)row0 * 128))[i];
        float4 xv4 = ((const float4*)(x + (size_t)row0 * 128))[i];
        int r = i >> 5, c4 = (i & 31) * 4;
        *(float4*)&xr[r * 128 + c4] = xv4;
        __hip_bfloat16* d = &ca[r * 136 + c4];
        d[0] = __float2bfloat16(cv4.x); d[1] = __float2bfloat16(cv4.y);
        d[2] = __float2bfloat16(cv4.z); d[3] = __float2bfloat16(cv4.w);
    }
    __syncthreads();
    int m = lane & 15, quad = lane >> 4;
    bf16x8 a1[4];
    #pragma unroll
    for (int kt = 0; kt < 4; kt++) a1[kt] = *(bf16x8*)&ca[m * 136 + kt * 32 + quad * 8];
    f32x4 acc2[2] = {{0.f,0.f,0.f,0.f}, {0.f,0.f,0.f,0.f}};
    #pragma unroll
    for (int kt = 0; kt < 4; kt++) {
        #pragma unroll
        for (int nt0 = 0; nt0 < 2; nt0++) {
            int nt = w * 2 + nt0;
            bf16x8 bfr = ((const bf16x8*)(Po + (size_t)nt * 4 * 512))[kt * 64 + lane];
            acc2[nt0] = __builtin_amdgcn_mfma_f32_16x16x32_bf16(a1[kt], bfr, acc2[nt0], 0, 0, 0);
        }
    }
    #pragma unroll
    for (int nt0 = 0; nt0 < 2; nt0++) {
        int n = (w * 2 + nt0) * 16 + m;
        #pragma unroll
        for (int r = 0; r < 4; r++) dbuf[(quad * 4 + r) * 132 + n] = acc2[nt0][r];
    }
    __syncthreads();
    #pragma unroll
    for (int rr = 0; rr < 4; rr++) {
        int row = w * 4 + rr;
        int c0 = lane, c1 = lane + 64;
        float y0 = dbuf[row * 132 + c0] + bias[c0] + xr[row * 128 + c0];
        float y1 = dbuf[row * 132 + c1] + bias[c1] + xr[row * 128 + c1];
        float sm = y0 + y1;
        #pragma unroll
        for (int o = 32; o > 0; o >>= 1) sm += __shfl_xor(sm, o);
        float mu = sm * (1.0f / 128.0f);
        float d0 = y0 - mu, d1 = y1 - mu;
        float vv = d0 * d0 + d1 * d1;
        #pragma unroll
        for (int o = 32; o > 0; o >>= 1) vv += __shfl_xor(vv, o);
        float rstd = rsqrtf(vv * (1.0f / 128.0f) + 1e-7f);
        x[(size_t)(row0 + row) * 128 + c0] = d0 * rstd * ln_s[c0] + ln_b[c0];
        x[(size_t)(row0 + row) * 128 + c1] = d1 * rstd * ln_s[c1] + ln_b[c1];
    }
}

// -------- fused FFN via MFMA: 16 rows/block (R12 win, unchanged) --------
__global__ __launch_bounds__(256) void ffn_mfma_kernel(const float* __restrict__ x,
                                                       const __hip_bfloat16* __restrict__ P1,
                                                       const float* __restrict__ b1,
                                                       const __hip_bfloat16* __restrict__ P2,
                                                       const float* __restrict__ b2,
                                                       const float* __restrict__ ln_s, const float* __restrict__ ln_b,
                                                       float* __restrict__ xout) {
    int blk = blockIdx.x;       // 0..1199
    int t = threadIdx.x;        // 0..255
    int w = t >> 6, lane = t & 63;
    int row0 = blk * 16;

    __shared__ __align__(16) __hip_bfloat16 xa[16 * 136];
    __shared__ float xr[16 * 128];
    __shared__ __align__(16) __hip_bfloat16 ha[16 * 520];
    __shared__ float dbuf[16 * 132];

    for (int i = t; i < 512; i += 256) {
        float4 v4 = ((const float4*)(x + (size_t)row0 * 128))[i];
        int r = i >> 5, c4 = (i & 31) * 4;
        *(float4*)&xr[r * 128 + c4] = v4;
        __hip_bfloat16* d = &xa[r * 136 + c4];
        d[0] = __float2bfloat16(v4.x); d[1] = __float2bfloat16(v4.y);
        d[2] = __float2bfloat16(v4.z); d[3] = __float2bfloat16(v4.w);
    }
    __syncthreads();

    int m = lane & 15, quad = lane >> 4;

    bf16x8 a1[4];
    #pragma unroll
    for (int kt = 0; kt < 4; kt++)
        a1[kt] = *(bf16x8*)&xa[m * 136 + kt * 32 + quad * 8];
    #pragma unroll
    for (int nt0 = 0; nt0 < 8; nt0++) {
        int nt = w * 8 + nt0;
        f32x4 acc = {0.f, 0.f, 0.f, 0.f};
        const bf16x8* bp = (const bf16x8*)(P1 + (size_t)nt * 4 * 512);
        #pragma unroll
        for (int kt = 0; kt < 4; kt++) {
            bf16x8 bfr = bp[kt * 64 + lane];
            acc = __builtin_amdgcn_mfma_f32_16x16x32_bf16(a1[kt], bfr, acc, 0, 0, 0);
        }
        int n = nt * 16 + m;
        float bb = b1[n];
        #pragma unroll
        for (int r = 0; r < 4; r++)
            ha[(quad * 4 + r) * 520 + n] = __float2bfloat16(gelu_f(acc[r] + bb));
    }
    __syncthreads();

    f32x4 acc2[2] = {{0.f,0.f,0.f,0.f}, {0.f,0.f,0.f,0.f}};
    #pragma unroll
    for (int kt = 0; kt < 16; kt++) {
        bf16x8 a = *(bf16x8*)&ha[m * 520 + kt * 32 + quad * 8];
        #pragma unroll
        for (int nt0 = 0; nt0 < 2; nt0++) {
            int nt = w * 2 + nt0;
            bf16x8 bfr = ((const bf16x8*)(P2 + (size_t)nt * 16 * 512))[kt * 64 + lane];
            acc2[nt0] = __builtin_amdgcn_mfma_f32_16x16x32_bf16(a, bfr, acc2[nt0], 0, 0, 0);
        }
    }
    #pragma unroll
    for (int nt0 = 0; nt0 < 2; nt0++) {
        int n = (w * 2 + nt0) * 16 + m;
        #pragma unroll
        for (int r = 0; r < 4; r++)
            dbuf[(quad * 4 + r) * 132 + n] = acc2[nt0][r];
    }
    __syncthreads();

    #pragma unroll
    for (int rr = 0; rr < 4; rr++) {
        int row = w * 4 + rr;
        int c0 = lane, c1 = lane + 64;
        float y0 = dbuf[row * 132 + c0] + b2[c0] + xr[row * 128 + c0];
        float y1 = dbuf[row * 132 + c1] + b2[c1] + xr[row * 128 + c1];
        float sm = y0 + y1;
        #pragma unroll
        for (int o = 32; o > 0; o >>= 1) sm += __shfl_xor(sm, o);
        float mu = sm * (1.0f / 128.0f);
        float d0 = y0 - mu, d1 = y1 - mu;
        float vv = d0 * d0 + d1 * d1;
        #pragma unroll
        for (int o = 32; o > 0; o >>= 1) vv += __shfl_xor(vv, o);
        float rstd = rsqrtf(vv * (1.0f / 128.0f) + 1e-7f);
        xout[(size_t)(row0 + row) * 128 + c0] = d0 * rstd * ln_s[c0] + ln_b[c0];
        xout[(size_t)(row0 + row) * 128 + c1] = d1 * rstd * ln_s[c1] + ln_b[c1];
    }
}

// -------- reconstruction MLP via MFMA: 16 rows/block; 128->128->64->5 --------
__global__ __launch_bounds__(256) void rec_mfma_kernel(const float* __restrict__ x,
                                                       const __hip_bfloat16* __restrict__ Pr1,
                                                       const float* __restrict__ b1,
                                                       const __hip_bfloat16* __restrict__ Pr2,
                                                       const float* __restrict__ b2,
                                                       const float* __restrict__ W3, const float* __restrict__ b3,
                                                       float* __restrict__ r3) {
    int blk = blockIdx.x;       // 0..1199
    int t = threadIdx.x;        // 0..255
    int w = t >> 6, lane = t & 63;
    int row0 = blk * 16;
    __shared__ __align__(16) __hip_bfloat16 xa[16 * 136];
    __shared__ __align__(16) __hip_bfloat16 ha[16 * 136];  // r1 bf16, A-layout staging
    __shared__ float r2s[16 * 68];                          // r2 fp32
    for (int i = t; i < 512; i += 256) {
        float4 v4 = ((const float4*)(x + (size_t)row0 * 128))[i];
        int r = i >> 5, c4 = (i & 31) * 4;
        __hip_bfloat16* d = &xa[r * 136 + c4];
        d[0] = __float2bfloat16(v4.x); d[1] = __float2bfloat16(v4.y);
        d[2] = __float2bfloat16(v4.z); d[3] = __float2bfloat16(v4.w);
    }
    __syncthreads();
    int m = lane & 15, quad = lane >> 4;

    // phase 1: r1 = gelu(x @ W1 + b1); N=128, 2 n-tiles/wave
    bf16x8 a1[4];
    #pragma unroll
    for (int kt = 0; kt < 4; kt++) a1[kt] = *(bf16x8*)&xa[m * 136 + kt * 32 + quad * 8];
    #pragma unroll
    for (int nt0 = 0; nt0 < 2; nt0++) {
        int nt = w * 2 + nt0;
        f32x4 acc = {0.f, 0.f, 0.f, 0.f};
        const bf16x8* bp = (const bf16x8*)(Pr1 + (size_t)nt * 4 * 512);
        #pragma unroll
        for (int kt = 0; kt < 4; kt++) {
            bf16x8 bfr = bp[kt * 64 + lane];
            acc = __builtin_amdgcn_mfma_f32_16x16x32_bf16(a1[kt], bfr, acc, 0, 0, 0);
        }
        int n = nt * 16 + m;
        float bb = b1[n];
        #pragma unroll
        for (int r = 0; r < 4; r++)
            ha[(quad * 4 + r) * 136 + n] = __float2bfloat16(gelu_f(acc[r] + bb));
    }
    __syncthreads();

    // phase 2: r2 = gelu(r1 @ W2 + b2); N=64, 1 n-tile/wave
    {
        f32x4 acc = {0.f, 0.f, 0.f, 0.f};
        const bf16x8* bp = (const bf16x8*)(Pr2 + (size_t)w * 4 * 512);
        #pragma unroll
        for (int kt = 0; kt < 4; kt++) {
            bf16x8 a = *(bf16x8*)&ha[m * 136 + kt * 32 + quad * 8];
            bf16x8 bfr = bp[kt * 64 + lane];
            acc = __builtin_amdgcn_mfma_f32_16x16x32_bf16(a, bfr, acc, 0, 0, 0);
        }
        int n = w * 16 + m;
        float bb = b2[n];
        #pragma unroll
        for (int r = 0; r < 4; r++)
            r2s[(quad * 4 + r) * 68 + n] = gelu_f(acc[r] + bb);
    }
    __syncthreads();

    // phase 3: r3 = gelu(r2 @ W3 + b3); [16 rows x 5 cols], VALU
    if (t < 80) {
        int row = t / 5, c = t % 5;
        float a = b3[c];
        for (int k = 0; k < 64; k++) a += r2s[row * 68 + k] * W3[k * 5 + c];
        r3[(size_t)(row0 + row) * 5 + c] = gelu_f(a);
    }
}

// -------- connection head v2 (R15 win, unchanged) --------
__global__ void conn_kernel(const float* __restrict__ r3, const float* __restrict__ W,
                            const float* __restrict__ b, void* out, const unsigned* maskw) {
    bool bfm = bf16_mode(maskw);
    int cb = blockIdx.x;     // 0..39
    int bg = blockIdx.y;     // 0..15
    int t = threadIdx.x;     // 0..255
    int cl = t & 63;
    int kq = t >> 6;
    int col = cb * 64 + cl;
    __shared__ float rs[4 * 1500];
    __shared__ float pacc[4 * 64 * 4];
    {
        const float4* src = (const float4*)(r3 + (size_t)bg * 4 * 1500);
        for (int i = t; i < 1500; i += 256) ((float4*)rs)[i] = src[i];
    }
    __syncthreads();
    float acc[4] = {0.f, 0.f, 0.f, 0.f};
    if (col < 2500) {
        for (int k = kq * 4; k < 1500; k += 16) {
            float w0 = W[(size_t)(k + 0) * 2500 + col];
            float w1 = W[(size_t)(k + 1) * 2500 + col];
            float w2 = W[(size_t)(k + 2) * 2500 + col];
            float w3 = W[(size_t)(k + 3) * 2500 + col];
            #pragma unroll
            for (int bb = 0; bb < 4; bb++) {
                float4 rv = *(const float4*)&rs[bb * 1500 + k];
                acc[bb] += rv.x * w0 + rv.y * w1 + rv.z * w2 + rv.w * w3;
            }
        }
    }
    #pragma unroll
    for (int bb = 0; bb < 4; bb++) pacc[(kq * 64 + cl) * 4 + bb] = acc[bb];
    __syncthreads();
    if (kq == 0 && col < 2500) {
        float bv = b[col];
        #pragma unroll
        for (int bb = 0; bb < 4; bb++) {
            float a = bv + pacc[(0 * 64 + cl) * 4 + bb] + pacc[(1 * 64 + cl) * 4 + bb]
                         + pacc[(2 * 64 + cl) * 4 + bb] + pacc[(3 * 64 + cl) * 4 + bb];
            int ob = bg * 4 + bb;
            if (bfm) ((__hip_bfloat16*)out)[(size_t)ob * 2500 + col] = __float2bfloat16(a);
            else     ((float*)out)[(size_t)ob * 2500 + col] = a;
        }
    }
}

extern "C" void kernel_launch(void* const* d_in, const int* in_sizes, int n_in,
                              void* d_out, int out_size, void* d_ws, size_t ws_size,
                              hipStream_t stream) {
    float* ws = (float*)d_ws;

    float* cv[NIN];
    size_t off = 0;
    for (int i = 0; i < NIN; i++) { cv[i] = ws + off; off += (size_t)in_sizes[i]; }

    const float* inp      = cv[0];
    const float* mask     = cv[1];
    const float* emb_W1   = cv[2];
    const float* emb_b1   = cv[3];
    const float* emb_W2   = cv[4];
    const float* emb_b2   = cv[5];
    const float* emb_W3   = cv[6];
    const float* emb_b3   = cv[7];
    const float* tok_emb  = cv[8];
    const float* emb_ln_s = cv[9];
    const float* emb_ln_b = cv[10];
    const float* rel_emb  = cv[11];
    const float* qkv_W    = cv[12];
    const float* q_bias   = cv[13];
    const float* v_bias   = cv[14];
    const float* pos_k_W  = cv[15];
    const float* pos_q_W  = cv[16];
    const float* pos_q_b  = cv[17];
    const float* attn_out_W = cv[18];
    const float* attn_out_b = cv[19];
    const float* ln1_s    = cv[20];
    const float* ln1_b    = cv[21];
    const float* ffn_W1   = cv[22];
    const float* ffn_b1   = cv[23];
    const float* ffn_W2   = cv[24];
    const float* ffn_b2   = cv[25];
    const float* ln2_s    = cv[26];
    const float* ln2_b    = cv[27];
    const float* rec_W1   = cv[28];
    const float* rec_b1   = cv[29];
    const float* rec_W2   = cv[30];
    const float* rec_b2   = cv[31];
    const float* rec_W3   = cv[32];
    const float* rec_b3   = cv[33];
    const float* conn_W   = cv[34];
    const float* conn_b   = cv[35];

    const int NTOK = Bq * Sq;            // 19200
    float* x    = ws + off;
    float* q    = x    + (size_t)NTOK * 128;
    float* k    = q    + (size_t)Bq * NH * Sq * 32;
    float* ctx  = k    + (size_t)Bq * NH * Sq * 32;
    float* c2p  = ctx  + (size_t)NTOK * 128;
    float* p2c  = c2p  + (size_t)Bq * NH * Sq * 16;
    float* posk = p2c  + (size_t)Bq * NH * Sq * 16;      // [NL][16][128]
    float* posq = posk + (size_t)NL * 16 * 128;
    float* r3b  = posq + (size_t)NL * 16 * 128;
    float* endf = r3b  + (size_t)NTOK * 5;
    __hip_bfloat16* P1 = (__hip_bfloat16*)endf;          // 8 x 65536 bf16
    __hip_bfloat16* P2 = P1 + (size_t)NL * 65536;
    __hip_bfloat16* Pq = P2 + (size_t)NL * 65536;        // 8 x 49152
    __hip_bfloat16* Po = Pq + (size_t)NL * 49152;        // 8 x 16384
    __hip_bfloat16* qbf = Po + (size_t)NL * 16384;       // 256*SP*32 each
    __hip_bfloat16* kbf = qbf + (size_t)256 * SP * 32;
    __hip_bfloat16* vTb = kbf + (size_t)256 * SP * 32;
    __hip_bfloat16* Pr1 = vTb + (size_t)256 * SP * 32;   // 16384
    __hip_bfloat16* Pr2 = Pr1 + 16384;                   // 8192
    __hip_bfloat16* Pe2 = Pr2 + 8192;                    // 8192  (emb_W2 packed)
    __hip_bfloat16* Pe3 = Pe2 + 8192;                    // 16384 (emb_W3 packed)

    const unsigned* maskw = (const unsigned*)d_in[1];

    ConvArgs ca;
    for (int i = 0; i < NIN; i++) {
        ca.src[i] = d_in[i];
        ca.dst[i] = cv[i];
        ca.n[i] = in_sizes[i];
    }
    convert_kernel<<<dim3(256, NIN), 256, 0, stream>>>(ca, maskw);
    pack_kernel<<<dim3(32, NL, 8), 256, 0, stream>>>(ffn_W1, ffn_W2, qkv_W, attn_out_W,
                                                     rec_W1, rec_W2, emb_W2, emb_W3,
                                                     P1, P2, Pq, Po, Pr1, Pr2, Pe2, Pe3);

    embed_mfma_kernel<<<NTOK / 16, 256, 0, stream>>>(inp, mask, emb_W1, emb_b1,
                                                     Pe2, emb_b2, Pe3, emb_b3,
                                                     tok_emb, emb_ln_s, emb_ln_b, x);

    // all-layer positional projections (hoisted out of the layer loop)
    pos_kernel<<<dim3(32, NL), 128, 0, stream>>>(rel_emb, pos_k_W, pos_q_W, pos_q_b, posk, posq);

    for (int l = 0; l < NL; l++) {
        qkv_mfma_kernel<<<NTOK / 16, 256, 0, stream>>>(x, Pq + (size_t)l * 49152,
                                                       q_bias + l * 128, v_bias + l * 128,
                                                       q, k, qbf, kbf, vTb);
        relscore_kernel<<<dim3(Bq * NH, 5), 256, 0, stream>>>(q, k, posk + (size_t)l * 2048,
                                                              posq + (size_t)l * 2048, c2p, p2c);
        attn_mfma_kernel<<<dim3(256, 5), 256, 0, stream>>>(qbf, kbf, vTb, c2p, p2c, mask, ctx);
        attnout_mfma_kernel<<<NTOK / 16, 256, 0, stream>>>(ctx, Po + (size_t)l * 16384,
                                                           attn_out_b + l * 128,
                                                           ln1_s + l * 128, ln1_b + l * 128, x);
        ffn_mfma_kernel<<<NTOK / 16, 256, 0, stream>>>(x, P1 + (size_t)l * 65536, ffn_b1 + l * 512,
                                                       P2 + (size_t)l * 65536, ffn_b2 + l * 128,
                                                       ln2_s + l * 128, ln2_b + l * 128, x);
    }

    rec_mfma_kernel<<<NTOK / 16, 256, 0, stream>>>(x, Pr1, rec_b1, Pr2, rec_b2,
                                                   rec_W3, rec_b3, r3b);
    conn_kernel<<<dim3(40, 16), 256, 0, stream>>>(r3b, conn_W, conn_b, d_out, maskw);
}

// Round 4
// 730.927 us; speedup vs baseline: 1.6858x; 1.5772x over previous
//
#include <hip/hip_runtime.h>
#include <hip/hip_bf16.h>
#include <math.h>

#define Bq 64
#define Sq 300
#define NH 4
#define DHd 32
#define Dd 128
#define NL 8
#define FF 512
#define NIN 36
#define SP 304   // padded seq for MFMA tiles
#define SPX 320  // j-range incl. last-tile overrun (10 tiles x 32)

typedef __attribute__((ext_vector_type(8))) short bf16x8;
typedef __attribute__((ext_vector_type(4))) float f32x4;

__device__ __forceinline__ float gelu_f(float x) {
    return 0.5f * x * (1.0f + erff(x * 0.70710678118654752f));
}
__device__ __forceinline__ bool bf16_mode(const unsigned* maskw) {
    return maskw[0] == 0x3F803F80u;   // two bf16 1.0s; f32 1.0 is 0x3F800000
}

// -------- dtype-agnostic input widening: all 36 inputs -> fp32 shadow in ws --------
struct ConvArgs {
    const void* src[NIN];
    float* dst[NIN];
    int n[NIN];
};

__global__ void convert_kernel(ConvArgs a, const unsigned* maskw) {
    bool bfm = bf16_mode(maskw);
    int bi = blockIdx.y;
    int n = a.n[bi];
    float* dst = a.dst[bi];
    int stride = gridDim.x * blockDim.x;
    int i0 = blockIdx.x * blockDim.x + threadIdx.x;
    if (bfm) {
        const __hip_bfloat16* s = (const __hip_bfloat16*)a.src[bi];
        for (int i = i0; i < n; i += stride) dst[i] = __bfloat162float(s[i]);
    } else {
        const float* s = (const float*)a.src[bi];
        for (int i = i0; i < n; i += stride) dst[i] = s[i];
    }
}

// -------- pack weights to MFMA B-operand layout [nt][kt][64][8] bf16 --------
// which: 0=ffn_W1(K128,N512) 1=ffn_W2(K512,N128) 2=qkv_W(K128,N384)
//        3=attn_out_W(K128,N128) 4=rec_W1(K128,N128,l=0) 5=rec_W2(K128,N64,l=0)
//        6=emb_W2(K64,N128,l=0) 7=emb_W3(K128,N128,l=0)
__global__ void pack_kernel(const float* __restrict__ W1all, const float* __restrict__ W2all,
                            const float* __restrict__ Wqall, const float* __restrict__ Woall,
                            const float* __restrict__ Wr1, const float* __restrict__ Wr2,
                            const float* __restrict__ We2, const float* __restrict__ We3,
                            __hip_bfloat16* __restrict__ P1, __hip_bfloat16* __restrict__ P2,
                            __hip_bfloat16* __restrict__ Pq, __hip_bfloat16* __restrict__ Po,
                            __hip_bfloat16* __restrict__ Pr1, __hip_bfloat16* __restrict__ Pr2,
                            __hip_bfloat16* __restrict__ Pe2, __hip_bfloat16* __restrict__ Pe3) {
    int l = blockIdx.y;
    int which = blockIdx.z;
    if (which >= 4 && l != 0) return;
    int K = (which == 1) ? 512 : ((which == 6) ? 64 : 128);
    int N = (which == 0) ? 512 : (which == 1 ? 128 : (which == 2 ? 384 : (which == 5 ? 64 : 128)));
    int slots = (K / 32) * (N / 16) * 64;
    int idx = blockIdx.x * 256 + threadIdx.x;
    if (idx >= slots) return;
    int lane = idx & 63;
    int nkt = K / 32;
    int kt = (idx >> 6) % nkt;
    int nt = (idx >> 6) / nkt;
    const float* W; __hip_bfloat16* P;
    switch (which) {
        case 0:  W = W1all + (size_t)l * 128 * 512; P = P1 + (size_t)l * 65536; break;
        case 1:  W = W2all + (size_t)l * 512 * 128; P = P2 + (size_t)l * 65536; break;
        case 2:  W = Wqall + (size_t)l * 128 * 384; P = Pq + (size_t)l * 49152; break;
        case 3:  W = Woall + (size_t)l * 128 * 128; P = Po + (size_t)l * 16384; break;
        case 4:  W = Wr1; P = Pr1; break;
        case 5:  W = Wr2; P = Pr2; break;
        case 6:  W = We2; P = Pe2; break;
        default: W = We3; P = Pe3; break;
    }
    P += (size_t)idx * 8;
    int n = nt * 16 + (lane & 15);
    int k0 = kt * 32 + (lane >> 4) * 8;
    #pragma unroll
    for (int j = 0; j < 8; j++) P[j] = __float2bfloat16(W[(size_t)(k0 + j) * N + n]);
}

// -------- embedding v3: MFMA for layers 2&3 (attnout-style), fp32 layer1 --------
__global__ __launch_bounds__(256) void embed_mfma_kernel(
        const float* __restrict__ inp, const float* __restrict__ mask,
        const float* __restrict__ W1, const float* __restrict__ b1,
        const __hip_bfloat16* __restrict__ Pe2, const float* __restrict__ b2,
        const __hip_bfloat16* __restrict__ Pe3, const float* __restrict__ b3,
        const float* __restrict__ tok_emb,
        const float* __restrict__ ln_s, const float* __restrict__ ln_b,
        float* __restrict__ x) {
    int blk = blockIdx.x;       // 0..1199
    int t = threadIdx.x;        // 0..255
    int w = t >> 6, lane = t & 63;
    int row0 = blk * 16;
    __shared__ float f[16][4];
    __shared__ __align__(16) __hip_bfloat16 e1a[16 * 72];   // layer1 out, A-layout
    __shared__ __align__(16) __hip_bfloat16 e2a[16 * 136];  // layer2 out, A-layout
    __shared__ float dbuf[16 * 132];
    if (t < 64) f[t >> 2][t & 3] = inp[(size_t)(row0 + (t >> 2)) * 4 + (t & 3)];
    __syncthreads();
    {   // layer1: 3->64 fp32, 4 outputs/thread, emit bf16
        int r1 = t >> 4, n0 = (t & 15) * 4;
        float f0 = f[r1][0], f1 = f[r1][1], f2 = f[r1][2];
        #pragma unroll
        for (int j = 0; j < 4; j++) {
            int n = n0 + j;
            float a = b1[n] + f0 * W1[n] + f1 * W1[64 + n] + f2 * W1[128 + n];
            e1a[r1 * 72 + n] = __float2bfloat16(gelu_f(a));
        }
    }
    __syncthreads();
    int m = lane & 15, quad = lane >> 4;
    // layer2 MFMA: K=64 (2 kt), N=128 (2 nt/wave)
    bf16x8 a2[2];
    #pragma unroll
    for (int kt = 0; kt < 2; kt++) a2[kt] = *(bf16x8*)&e1a[m * 72 + kt * 32 + quad * 8];
    #pragma unroll
    for (int nt0 = 0; nt0 < 2; nt0++) {
        int nt = w * 2 + nt0;
        f32x4 acc = {0.f, 0.f, 0.f, 0.f};
        const bf16x8* bp = (const bf16x8*)(Pe2 + (size_t)nt * 2 * 512);
        #pragma unroll
        for (int kt = 0; kt < 2; kt++) {
            bf16x8 bfr = bp[kt * 64 + lane];
            acc = __builtin_amdgcn_mfma_f32_16x16x32_bf16(a2[kt], bfr, acc, 0, 0, 0);
        }
        int n = nt * 16 + m;
        float bb = b2[n];
        #pragma unroll
        for (int r = 0; r < 4; r++)
            e2a[(quad * 4 + r) * 136 + n] = __float2bfloat16(gelu_f(acc[r] + bb));
    }
    __syncthreads();
    // layer3 MFMA: K=128 (4 kt), N=128 (2 nt/wave); epilogue gelu + tok_emb
    bf16x8 a3[4];
    #pragma unroll
    for (int kt = 0; kt < 4; kt++) a3[kt] = *(bf16x8*)&e2a[m * 136 + kt * 32 + quad * 8];
    f32x4 acc2[2] = {{0.f,0.f,0.f,0.f}, {0.f,0.f,0.f,0.f}};
    #pragma unroll
    for (int kt = 0; kt < 4; kt++) {
        #pragma unroll
        for (int nt0 = 0; nt0 < 2; nt0++) {
            int nt = w * 2 + nt0;
            bf16x8 bfr = ((const bf16x8*)(Pe3 + (size_t)nt * 4 * 512))[kt * 64 + lane];
            acc2[nt0] = __builtin_amdgcn_mfma_f32_16x16x32_bf16(a3[kt], bfr, acc2[nt0], 0, 0, 0);
        }
    }
    #pragma unroll
    for (int nt0 = 0; nt0 < 2; nt0++) {
        int n = (w * 2 + nt0) * 16 + m;
        float bb = b3[n];
        #pragma unroll
        for (int r = 0; r < 4; r++) {
            int row = quad * 4 + r;
            int tok = (int)f[row][3];
            dbuf[row * 132 + n] = gelu_f(acc2[nt0][r] + bb) + tok_emb[tok * 128 + n];
        }
    }
    __syncthreads();
    #pragma unroll
    for (int rr = 0; rr < 4; rr++) {
        int row = w * 4 + rr;
        int c0 = lane, c1 = lane + 64;
        float y0 = dbuf[row * 132 + c0];
        float y1 = dbuf[row * 132 + c1];
        float sm = y0 + y1;
        #pragma unroll
        for (int o = 32; o > 0; o >>= 1) sm += __shfl_xor(sm, o);
        float mu = sm * (1.0f / 128.0f);
        float d0 = y0 - mu, d1 = y1 - mu;
        float vv = d0 * d0 + d1 * d1;
        #pragma unroll
        for (int o = 32; o > 0; o >>= 1) vv += __shfl_xor(vv, o);
        float rstd = rsqrtf(vv * (1.0f / 128.0f) + 1e-7f);
        float mk = mask[row0 + row];
        x[(size_t)(row0 + row) * 128 + c0] = (d0 * rstd * ln_s[c0] + ln_b[c0]) * mk;
        x[(size_t)(row0 + row) * 128 + c1] = (d1 * rstd * ln_s[c1] + ln_b[c1]) * mk;
    }
}

// -------- qkv via MFMA: emits ONLY bf16 q/k [bh][SP][32] and vT [bh][32][SP] --------
__global__ __launch_bounds__(256) void qkv_mfma_kernel(const float* __restrict__ x,
                                                       const __hip_bfloat16* __restrict__ Pq,
                                                       const float* __restrict__ qb, const float* __restrict__ vb,
                                                       __hip_bfloat16* __restrict__ qbf,
                                                       __hip_bfloat16* __restrict__ kbf,
                                                       __hip_bfloat16* __restrict__ vT) {
    int blk = blockIdx.x;       // 0..1199
    int t = threadIdx.x;        // 0..255
    int w = t >> 6, lane = t & 63;
    int row0 = blk * 16;
    __shared__ __align__(16) __hip_bfloat16 xa[16 * 136];
    for (int i = t; i < 512; i += 256) {
        float4 v4 = ((const float4*)(x + (size_t)row0 * 128))[i];
        int r = i >> 5, c4 = (i & 31) * 4;
        __hip_bfloat16* d = &xa[r * 136 + c4];
        d[0] = __float2bfloat16(v4.x); d[1] = __float2bfloat16(v4.y);
        d[2] = __float2bfloat16(v4.z); d[3] = __float2bfloat16(v4.w);
    }
    __syncthreads();
    int m = lane & 15, quad = lane >> 4;
    bf16x8 a1[4];
    #pragma unroll
    for (int kt = 0; kt < 4; kt++) a1[kt] = *(bf16x8*)&xa[m * 136 + kt * 32 + quad * 8];
    const float inv_scale = 0.10206207261596576f;  // 1/sqrt(96)
    #pragma unroll
    for (int nt0 = 0; nt0 < 6; nt0++) {
        int nt = w * 6 + nt0;
        f32x4 acc = {0.f, 0.f, 0.f, 0.f};
        const bf16x8* bp = (const bf16x8*)(Pq + (size_t)nt * 4 * 512);
        #pragma unroll
        for (int kt = 0; kt < 4; kt++) {
            bf16x8 bfr = bp[kt * 64 + lane];
            acc = __builtin_amdgcn_mfma_f32_16x16x32_bf16(a1[kt], bfr, acc, 0, 0, 0);
        }
        int n = nt * 16 + m;
        int h = n / 96, mm = (n % 96) / 32, d = n % 32;
        float qbv = qb[h * 32 + d], vbv = vb[h * 32 + d];
        #pragma unroll
        for (int r = 0; r < 4; r++) {
            int row = row0 + quad * 4 + r;
            int bb = row / Sq, s = row % Sq;
            int bh = bb * NH + h;
            float a = acc[r];
            if (mm == 0) {
                qbf[((size_t)bh * SP + s) * 32 + d] = __float2bfloat16((a + qbv) * inv_scale);
            } else if (mm == 1) {
                kbf[((size_t)bh * SP + s) * 32 + d] = __float2bfloat16(a);
            } else {
                vT[((size_t)bh * 32 + d) * SP + s] = __float2bfloat16(a + vbv);
            }
        }
    }
}

// -------- zero the never-written padding rows/cols (once, before layer loop) --------
__global__ void pad_kernel(__hip_bfloat16* qbf, __hip_bfloat16* kbf, __hip_bfloat16* vT) {
    int i = blockIdx.x * 256 + threadIdx.x;   // 256 bh * 4 s * 32 d = 32768
    if (i >= 256 * 4 * 32) return;
    int bh = i >> 7, s = Sq + ((i >> 5) & 3), d = i & 31;
    __hip_bfloat16 z = __float2bfloat16(0.0f);
    qbf[((size_t)bh * SP + s) * 32 + d] = z;
    kbf[((size_t)bh * SP + s) * 32 + d] = z;
    vT[((size_t)bh * 32 + d) * SP + s] = z;
}

// -------- positional projections -> bf16 MFMA-B layout [L][NH][16 r][32 d] --------
__global__ void pos_kernel(const float* __restrict__ rel_emb,
                           const float* __restrict__ pkW_all, const float* __restrict__ pqW_all,
                           const float* __restrict__ pqb_all,
                           __hip_bfloat16* __restrict__ poskb, __hip_bfloat16* __restrict__ posqb) {
    int l = blockIdx.y;         // 0..NL-1
    int bi = blockIdx.x;        // 0..31
    int which = bi >> 4;        // 0: posk, 1: posq
    int r = bi & 15;
    int t = threadIdx.x;        // 0..127 = h*32+d
    __shared__ float re[128];
    re[t] = rel_emb[r * 128 + t];
    __syncthreads();
    const float* W = (which ? pqW_all : pkW_all) + (size_t)l * 128 * 128;
    float a = 0.0f;
    for (int k = 0; k < 128; k++) a += re[k] * W[k * 128 + t];
    int h = t >> 5, d = t & 31;
    size_t o = ((size_t)(l * NH + h) * 16 + r) * 32 + d;
    if (which) { a = (a + pqb_all[l * 128 + t]) * 0.10206207261596576f; posqb[o] = __float2bfloat16(a); }
    else       { poskb[o] = __float2bfloat16(a); }
}

// -------- MFMA attention v2: swapped QK^T, in-kernel c2p/p2c via MFMA, mask fold --------
__global__ __launch_bounds__(256) void attn_mfma_kernel(const __hip_bfloat16* __restrict__ qbf,
                                                        const __hip_bfloat16* __restrict__ kbf,
                                                        const __hip_bfloat16* __restrict__ vT,
                                                        const __hip_bfloat16* __restrict__ poskb,
                                                        const __hip_bfloat16* __restrict__ posqb,
                                                        const float* __restrict__ mask, float* __restrict__ ctx) {
    int bh = blockIdx.x;            // 0..255
    int b = bh >> 2, h = bh & 3;
    int t = threadIdx.x;
    int w = t >> 6, lane = t & 63;
    int m = lane & 15, quad = lane >> 4;

    __shared__ float p2cS[SPX * 17];                        // 21760 B, block-shared
    __shared__ float c2pS[4][16 * 17];                      // per-wave
    __shared__ __align__(16) __hip_bfloat16 pT[4][16 * 40]; // per-wave P, [q][j] layout

    // ---- stage p2cS[j][r] = k[j].posq[r] via MFMA, with mask/padding folded to -3e4 ----
    {
        bf16x8 pqf = *(const bf16x8*)&posqb[(h * 16 + m) * 32 + quad * 8];
        #pragma unroll
        for (int it = 0; it < 5; it++) {
            int jb = (w + it * 4) * 16;
            bf16x8 kf2 = *(const bf16x8*)&kbf[((size_t)bh * SP + jb + m) * 32 + quad * 8];
            f32x4 pc = __builtin_amdgcn_mfma_f32_16x16x32_bf16(kf2, pqf, (f32x4){0.f,0.f,0.f,0.f}, 0, 0, 0);
            #pragma unroll
            for (int r = 0; r < 4; r++) {
                int j = jb + quad * 4 + r;                  // D row = A(K) row
                float mv = (j < Sq) ? mask[b * Sq + j] : 0.0f;
                p2cS[j * 17 + m] = (mv > 0.0f) ? pc[r] : -30000.0f;
            }
        }
    }
    __syncthreads();

    int qt = blockIdx.y * 4 + w;    // 0..19
    if (qt >= 19) return;           // no barriers after this point
    int q0 = qt * 16;

    float* c2pW = c2pS[w];
    __hip_bfloat16* pTW = pT[w];

    bf16x8 aq = *(const bf16x8*)&qbf[((size_t)bh * SP + q0 + m) * 32 + quad * 8];

    // ---- c2pW[q][r] = q[q].posk[r] via one MFMA (wave-private) ----
    {
        bf16x8 pkf = *(const bf16x8*)&poskb[(h * 16 + m) * 32 + quad * 8];
        f32x4 cc = __builtin_amdgcn_mfma_f32_16x16x32_bf16(aq, pkf, (f32x4){0.f,0.f,0.f,0.f}, 0, 0, 0);
        #pragma unroll
        for (int r = 0; r < 4; r++) c2pW[(quad * 4 + r) * 17 + m] = cc[r];
    }

    int qi = q0 + m;                // this lane's q-row (swapped layout)
    f32x4 oacc[2] = {{0.f,0.f,0.f,0.f}, {0.f,0.f,0.f,0.f}};
    float lacc = 0.0f;

    for (int jt2 = 0; jt2 < 10; jt2++) {
        int j0 = jt2 * 32;
        #pragma unroll
        for (int half = 0; half < 2; half++) {
            int jh = j0 + half * 16;
            bf16x8 kf = *(const bf16x8*)&kbf[((size_t)bh * SP + jh + m) * 32 + quad * 8];
            // swapped: S^T[j][q] = mfma(A=K rows j, B=Q^T); lane: col q=m, rows j=jh+quad*4+r
            f32x4 sc = __builtin_amdgcn_mfma_f32_16x16x32_bf16(kf, aq, (f32x4){0.f,0.f,0.f,0.f}, 0, 0, 0);
            int jb2 = jh + quad * 4;
            int base = qi - jb2 + 8;
            __hip_bfloat16 pb[4];
            #pragma unroll
            for (int r = 0; r < 4; r++) {
                int rr = base - r; rr = rr < 0 ? 0 : (rr > 15 ? 15 : rr);
                float sv = sc[r] + c2pW[m * 17 + rr] + p2cS[(jb2 + r) * 17 + rr];
                float p = __expf(sv);
                lacc += p;
                pb[r] = __float2bfloat16(p);
            }
            *(uint2*)&pTW[m * 40 + half * 16 + quad * 4] = *(uint2*)pb;   // packed 4x bf16
        }
        bf16x8 ap = *(bf16x8*)&pTW[m * 40 + quad * 8];
        #pragma unroll
        for (int nt = 0; nt < 2; nt++) {
            bf16x8 vf = *(const bf16x8*)&vT[((size_t)bh * 32 + nt * 16 + m) * SP + j0 + quad * 8];
            oacc[nt] = __builtin_amdgcn_mfma_f32_16x16x32_bf16(ap, vf, oacc[nt], 0, 0, 0);
        }
    }

    // ---- softmax denominator: lane(m,*) holds partials for q=m ----
    lacc += __shfl_xor(lacc, 16);
    lacc += __shfl_xor(lacc, 32);
    #pragma unroll
    for (int r = 0; r < 4; r++) {
        int qrow = quad * 4 + r;
        float lr = __shfl(lacc, qrow);      // lane qrow holds l[q0+qrow]
        int qi2 = q0 + qrow;
        float qm = (qi2 < Sq) ? mask[b * Sq + qi2] : 0.0f;
        float inv = (qm > 0.0f && lr > 0.0f) ? 1.0f / lr : 0.0f;
        if (qi2 < Sq) {
            size_t base2 = ((size_t)(b * Sq + qi2)) * 128 + h * 32;
            ctx[base2 + m]      = oacc[0][r] * inv;
            ctx[base2 + 16 + m] = oacc[1][r] * inv;
        }
    }
}

// -------- attn_out via MFMA: 16 rows/block, N=128 + residual + LN --------
__global__ __launch_bounds__(256) void attnout_mfma_kernel(const float* __restrict__ ctx,
                                                           const __hip_bfloat16* __restrict__ Po,
                                                           const float* __restrict__ bias,
                                                           const float* __restrict__ ln_s, const float* __restrict__ ln_b,
                                                           float* __restrict__ x) {
    int blk = blockIdx.x;       // 0..1199
    int t = threadIdx.x;        // 0..255
    int w = t >> 6, lane = t & 63;
    int row0 = blk * 16;
    __shared__ __align__(16) __hip_bfloat16 ca[16 * 136];
    __shared__ float xr[16 * 128];
    __shared__ float dbuf[16 * 132];
    for (int i = t; i < 512; i += 256) {
        float4 cv4 = ((const float4*)(ctx + (size_t)row0 * 128))[i];
        float4 xv4 = ((const float4*)(x + (size_t)row0 * 128))[i];
        int r = i >> 5, c4 = (i & 31) * 4;
        *(float4*)&xr[r * 128 + c4] = xv4;
        __hip_bfloat16* d = &ca[r * 136 + c4];
        d[0] = __float2bfloat16(cv4.x); d[1] = __float2bfloat16(cv4.y);
        d[2] = __float2bfloat16(cv4.z); d[3] = __float2bfloat16(cv4.w);
    }
    __syncthreads();
    int m = lane & 15, quad = lane >> 4;
    bf16x8 a1[4];
    #pragma unroll
    for (int kt = 0; kt < 4; kt++) a1[kt] = *(bf16x8*)&ca[m * 136 + kt * 32 + quad * 8];
    f32x4 acc2[2] = {{0.f,0.f,0.f,0.f}, {0.f,0.f,0.f,0.f}};
    #pragma unroll
    for (int kt = 0; kt < 4; kt++) {
        #pragma unroll
        for (int nt0 = 0; nt0 < 2; nt0++) {
            int nt = w * 2 + nt0;
            bf16x8 bfr = ((const bf16x8*)(Po + (size_t)nt * 4 * 512))[kt * 64 + lane];
            acc2[nt0] = __builtin_amdgcn_mfma_f32_16x16x32_bf16(a1[kt], bfr, acc2[nt0], 0, 0, 0);
        }
    }
    #pragma unroll
    for (int nt0 = 0; nt0 < 2; nt0++) {
        int n = (w * 2 + nt0) * 16 + m;
        #pragma unroll
        for (int r = 0; r < 4; r++) dbuf[(quad * 4 + r) * 132 + n] = acc2[nt0][r];
    }
    __syncthreads();
    #pragma unroll
    for (int rr = 0; rr < 4; rr++) {
        int row = w * 4 + rr;
        int c0 = lane, c1 = lane + 64;
        float y0 = dbuf[row * 132 + c0] + bias[c0] + xr[row * 128 + c0];
        float y1 = dbuf[row * 132 + c1] + bias[c1] + xr[row * 128 + c1];
        float sm = y0 + y1;
        #pragma unroll
        for (int o = 32; o > 0; o >>= 1) sm += __shfl_xor(sm, o);
        float mu = sm * (1.0f / 128.0f);
        float d0 = y0 - mu, d1 = y1 - mu;
        float vv = d0 * d0 + d1 * d1;
        #pragma unroll
        for (int o = 32; o > 0; o >>= 1) vv += __shfl_xor(vv, o);
        float rstd = rsqrtf(vv * (1.0f / 128.0f) + 1e-7f);
        x[(size_t)(row0 + row) * 128 + c0] = d0 * rstd * ln_s[c0] + ln_b[c0];
        x[(size_t)(row0 + row) * 128 + c1] = d1 * rstd * ln_s[c1] + ln_b[c1];
    }
}

// -------- fused FFN via MFMA: 16 rows/block (R12 win, unchanged) --------
__global__ __launch_bounds__(256) void ffn_mfma_kernel(const float* __restrict__ x,
                                                       const __hip_bfloat16* __restrict__ P1,
                                                       const float* __restrict__ b1,
                                                       const __hip_bfloat16* __restrict__ P2,
                                                       const float* __restrict__ b2,
                                                       const float* __restrict__ ln_s, const float* __restrict__ ln_b,
                                                       float* __restrict__ xout) {
    int blk = blockIdx.x;       // 0..1199
    int t = threadIdx.x;        // 0..255
    int w = t >> 6, lane = t & 63;
    int row0 = blk * 16;

    __shared__ __align__(16) __hip_bfloat16 xa[16 * 136];
    __shared__ float xr[16 * 128];
    __shared__ __align__(16) __hip_bfloat16 ha[16 * 520];
    __shared__ float dbuf[16 * 132];

    for (int i = t; i < 512; i += 256) {
        float4 v4 = ((const float4*)(x + (size_t)row0 * 128))[i];
        int r = i >> 5, c4 = (i & 31) * 4;
        *(float4*)&xr[r * 128 + c4] = v4;
        __hip_bfloat16* d = &xa[r * 136 + c4];
        d[0] = __float2bfloat16(v4.x); d[1] = __float2bfloat16(v4.y);
        d[2] = __float2bfloat16(v4.z); d[3] = __float2bfloat16(v4.w);
    }
    __syncthreads();

    int m = lane & 15, quad = lane >> 4;

    bf16x8 a1[4];
    #pragma unroll
    for (int kt = 0; kt < 4; kt++)
        a1[kt] = *(bf16x8*)&xa[m * 136 + kt * 32 + quad * 8];
    #pragma unroll
    for (int nt0 = 0; nt0 < 8; nt0++) {
        int nt = w * 8 + nt0;
        f32x4 acc = {0.f, 0.f, 0.f, 0.f};
        const bf16x8* bp = (const bf16x8*)(P1 + (size_t)nt * 4 * 512);
        #pragma unroll
        for (int kt = 0; kt < 4; kt++) {
            bf16x8 bfr = bp[kt * 64 + lane];
            acc = __builtin_amdgcn_mfma_f32_16x16x32_bf16(a1[kt], bfr, acc, 0, 0, 0);
        }
        int n = nt * 16 + m;
        float bb = b1[n];
        #pragma unroll
        for (int r = 0; r < 4; r++)
            ha[(quad * 4 + r) * 520 + n] = __float2bfloat16(gelu_f(acc[r] + bb));
    }
    __syncthreads();

    f32x4 acc2[2] = {{0.f,0.f,0.f,0.f}, {0.f,0.f,0.f,0.f}};
    #pragma unroll
    for (int kt = 0; kt < 16; kt++) {
        bf16x8 a = *(bf16x8*)&ha[m * 520 + kt * 32 + quad * 8];
        #pragma unroll
        for (int nt0 = 0; nt0 < 2; nt0++) {
            int nt = w * 2 + nt0;
            bf16x8 bfr = ((const bf16x8*)(P2 + (size_t)nt * 16 * 512))[kt * 64 + lane];
            acc2[nt0] = __builtin_amdgcn_mfma_f32_16x16x32_bf16(a, bfr, acc2[nt0], 0, 0, 0);
        }
    }
    #pragma unroll
    for (int nt0 = 0; nt0 < 2; nt0++) {
        int n = (w * 2 + nt0) * 16 + m;
        #pragma unroll
        for (int r = 0; r < 4; r++)
            dbuf[(quad * 4 + r) * 132 + n] = acc2[nt0][r];
    }
    __syncthreads();

    #pragma unroll
    for (int rr = 0; rr < 4; rr++) {
        int row = w * 4 + rr;
        int c0 = lane, c1 = lane + 64;
        float y0 = dbuf[row * 132 + c0] + b2[c0] + xr[row * 128 + c0];
        float y1 = dbuf[row * 132 + c1] + b2[c1] + xr[row * 128 + c1];
        float sm = y0 + y1;
        #pragma unroll
        for (int o = 32; o > 0; o >>= 1) sm += __shfl_xor(sm, o);
        float mu = sm * (1.0f / 128.0f);
        float d0 = y0 - mu, d1 = y1 - mu;
        float vv = d0 * d0 + d1 * d1;
        #pragma unroll
        for (int o = 32; o > 0; o >>= 1) vv += __shfl_xor(vv, o);
        float rstd = rsqrtf(vv * (1.0f / 128.0f) + 1e-7f);
        xout[(size_t)(row0 + row) * 128 + c0] = d0 * rstd * ln_s[c0] + ln_b[c0];
        xout[(size_t)(row0 + row) * 128 + c1] = d1 * rstd * ln_s[c1] + ln_b[c1];
    }
}

// -------- reconstruction MLP via MFMA: 16 rows/block; 128->128->64->5 --------
__global__ __launch_bounds__(256) void rec_mfma_kernel(const float* __restrict__ x,
                                                       const __hip_bfloat16* __restrict__ Pr1,
                                                       const float* __restrict__ b1,
                                                       const __hip_bfloat16* __restrict__ Pr2,
                                                       const float* __restrict__ b2,
                                                       const float* __restrict__ W3, const float* __restrict__ b3,
                                                       float* __restrict__ r3) {
    int blk = blockIdx.x;       // 0..1199
    int t = threadIdx.x;        // 0..255
    int w = t >> 6, lane = t & 63;
    int row0 = blk * 16;
    __shared__ __align__(16) __hip_bfloat16 xa[16 * 136];
    __shared__ __align__(16) __hip_bfloat16 ha[16 * 136];
    __shared__ float r2s[16 * 68];
    for (int i = t; i < 512; i += 256) {
        float4 v4 = ((const float4*)(x + (size_t)row0 * 128))[i];
        int r = i >> 5, c4 = (i & 31) * 4;
        __hip_bfloat16* d = &xa[r * 136 + c4];
        d[0] = __float2bfloat16(v4.x); d[1] = __float2bfloat16(v4.y);
        d[2] = __float2bfloat16(v4.z); d[3] = __float2bfloat16(v4.w);
    }
    __syncthreads();
    int m = lane & 15, quad = lane >> 4;

    bf16x8 a1[4];
    #pragma unroll
    for (int kt = 0; kt < 4; kt++) a1[kt] = *(bf16x8*)&xa[m * 136 + kt * 32 + quad * 8];
    #pragma unroll
    for (int nt0 = 0; nt0 < 2; nt0++) {
        int nt = w * 2 + nt0;
        f32x4 acc = {0.f, 0.f, 0.f, 0.f};
        const bf16x8* bp = (const bf16x8*)(Pr1 + (size_t)nt * 4 * 512);
        #pragma unroll
        for (int kt = 0; kt < 4; kt++) {
            bf16x8 bfr = bp[kt * 64 + lane];
            acc = __builtin_amdgcn_mfma_f32_16x16x32_bf16(a1[kt], bfr, acc, 0, 0, 0);
        }
        int n = nt * 16 + m;
        float bb = b1[n];
        #pragma unroll
        for (int r = 0; r < 4; r++)
            ha[(quad * 4 + r) * 136 + n] = __float2bfloat16(gelu_f(acc[r] + bb));
    }
    __syncthreads();

    {
        f32x4 acc = {0.f, 0.f, 0.f, 0.f};
        const bf16x8* bp = (const bf16x8*)(Pr2 + (size_t)w * 4 * 512);
        #pragma unroll
        for (int kt = 0; kt < 4; kt++) {
            bf16x8 a = *(bf16x8*)&ha[m * 136 + kt * 32 + quad * 8];
            bf16x8 bfr = bp[kt * 64 + lane];
            acc = __builtin_amdgcn_mfma_f32_16x16x32_bf16(a, bfr, acc, 0, 0, 0);
        }
        int n = w * 16 + m;
        float bb = b2[n];
        #pragma unroll
        for (int r = 0; r < 4; r++)
            r2s[(quad * 4 + r) * 68 + n] = gelu_f(acc[r] + bb);
    }
    __syncthreads();

    if (t < 80) {
        int row = t / 5, c = t % 5;
        float a = b3[c];
        for (int k = 0; k < 64; k++) a += r2s[row * 68 + k] * W3[k * 5 + c];
        r3[(size_t)(row0 + row) * 5 + c] = gelu_f(a);
    }
}

// -------- connection head v2 (R15 win, unchanged) --------
__global__ void conn_kernel(const float* __restrict__ r3, const float* __restrict__ W,
                            const float* __restrict__ b, void* out, const unsigned* maskw) {
    bool bfm = bf16_mode(maskw);
    int cb = blockIdx.x;     // 0..39
    int bg = blockIdx.y;     // 0..15
    int t = threadIdx.x;     // 0..255
    int cl = t & 63;
    int kq = t >> 6;
    int col = cb * 64 + cl;
    __shared__ float rs[4 * 1500];
    __shared__ float pacc[4 * 64 * 4];
    {
        const float4* src = (const float4*)(r3 + (size_t)bg * 4 * 1500);
        for (int i = t; i < 1500; i += 256) ((float4*)rs)[i] = src[i];
    }
    __syncthreads();
    float acc[4] = {0.f, 0.f, 0.f, 0.f};
    if (col < 2500) {
        for (int k = kq * 4; k < 1500; k += 16) {
            float w0 = W[(size_t)(k + 0) * 2500 + col];
            float w1 = W[(size_t)(k + 1) * 2500 + col];
            float w2 = W[(size_t)(k + 2) * 2500 + col];
            float w3 = W[(size_t)(k + 3) * 2500 + col];
            #pragma unroll
            for (int bb = 0; bb < 4; bb++) {
                float4 rv = *(const float4*)&rs[bb * 1500 + k];
                acc[bb] += rv.x * w0 + rv.y * w1 + rv.z * w2 + rv.w * w3;
            }
        }
    }
    #pragma unroll
    for (int bb = 0; bb < 4; bb++) pacc[(kq * 64 + cl) * 4 + bb] = acc[bb];
    __syncthreads();
    if (kq == 0 && col < 2500) {
        float bv = b[col];
        #pragma unroll
        for (int bb = 0; bb < 4; bb++) {
            float a = bv + pacc[(0 * 64 + cl) * 4 + bb] + pacc[(1 * 64 + cl) * 4 + bb]
                         + pacc[(2 * 64 + cl) * 4 + bb] + pacc[(3 * 64 + cl) * 4 + bb];
            int ob = bg * 4 + bb;
            if (bfm) ((__hip_bfloat16*)out)[(size_t)ob * 2500 + col] = __float2bfloat16(a);
            else     ((float*)out)[(size_t)ob * 2500 + col] = a;
        }
    }
}

extern "C" void kernel_launch(void* const* d_in, const int* in_sizes, int n_in,
                              void* d_out, int out_size, void* d_ws, size_t ws_size,
                              hipStream_t stream) {
    float* ws = (float*)d_ws;

    float* cv[NIN];
    size_t off = 0;
    for (int i = 0; i < NIN; i++) { cv[i] = ws + off; off += (size_t)in_sizes[i]; }

    const float* inp      = cv[0];
    const float* mask     = cv[1];
    const float* emb_W1   = cv[2];
    const float* emb_b1   = cv[3];
    const float* emb_W2   = cv[4];
    const float* emb_b2   = cv[5];
    const float* emb_W3   = cv[6];
    const float* emb_b3   = cv[7];
    const float* tok_emb  = cv[8];
    const float* emb_ln_s = cv[9];
    const float* emb_ln_b = cv[10];
    const float* rel_emb  = cv[11];
    const float* qkv_W    = cv[12];
    const float* q_bias   = cv[13];
    const float* v_bias   = cv[14];
    const float* pos_k_W  = cv[15];
    const float* pos_q_W  = cv[16];
    const float* pos_q_b  = cv[17];
    const float* attn_out_W = cv[18];
    const float* attn_out_b = cv[19];
    const float* ln1_s    = cv[20];
    const float* ln1_b    = cv[21];
    const float* ffn_W1   = cv[22];
    const float* ffn_b1   = cv[23];
    const float* ffn_W2   = cv[24];
    const float* ffn_b2   = cv[25];
    const float* ln2_s    = cv[26];
    const float* ln2_b    = cv[27];
    const float* rec_W1   = cv[28];
    const float* rec_b1   = cv[29];
    const float* rec_W2   = cv[30];
    const float* rec_b2   = cv[31];
    const float* rec_W3   = cv[32];
    const float* rec_b3   = cv[33];
    const float* conn_W   = cv[34];
    const float* conn_b   = cv[35];

    const int NTOK = Bq * Sq;            // 19200
    float* x    = ws + off;
    float* q    = x    + (size_t)NTOK * 128;             // (unused, kept for layout)
    float* k    = q    + (size_t)Bq * NH * Sq * 32;      // (unused)
    float* ctx  = k    + (size_t)Bq * NH * Sq * 32;
    float* c2p  = ctx  + (size_t)NTOK * 128;             // (unused)
    float* p2c  = c2p  + (size_t)Bq * NH * Sq * 16;      // (unused)
    float* posk = p2c  + (size_t)Bq * NH * Sq * 16;      // (unused)
    float* posq = posk + (size_t)NL * 16 * 128;          // (unused)
    float* r3b  = posq + (size_t)NL * 16 * 128;
    float* endf = r3b  + (size_t)NTOK * 5;
    __hip_bfloat16* P1 = (__hip_bfloat16*)endf;          // 8 x 65536 bf16
    __hip_bfloat16* P2 = P1 + (size_t)NL * 65536;
    __hip_bfloat16* Pq = P2 + (size_t)NL * 65536;        // 8 x 49152
    __hip_bfloat16* Po = Pq + (size_t)NL * 49152;        // 8 x 16384
    __hip_bfloat16* qbf = Po + (size_t)NL * 16384;       // 256*SP*32 each
    __hip_bfloat16* kbf = qbf + (size_t)256 * SP * 32;
    __hip_bfloat16* vTb = kbf + (size_t)256 * SP * 32;
    __hip_bfloat16* Pr1 = vTb + (size_t)256 * SP * 32;   // 16384
    __hip_bfloat16* Pr2 = Pr1 + 16384;                   // 8192
    __hip_bfloat16* Pe2 = Pr2 + 8192;                    // 8192
    __hip_bfloat16* Pe3 = Pe2 + 8192;                    // 16384
    __hip_bfloat16* Pkb = Pe3 + 16384;                   // [NL][NH][16][32] = 16384
    __hip_bfloat16* Pqb = Pkb + (size_t)NL * 2048;       // same

    const unsigned* maskw = (const unsigned*)d_in[1];

    ConvArgs ca;
    for (int i = 0; i < NIN; i++) {
        ca.src[i] = d_in[i];
        ca.dst[i] = cv[i];
        ca.n[i] = in_sizes[i];
    }
    convert_kernel<<<dim3(256, NIN), 256, 0, stream>>>(ca, maskw);
    pack_kernel<<<dim3(32, NL, 8), 256, 0, stream>>>(ffn_W1, ffn_W2, qkv_W, attn_out_W,
                                                     rec_W1, rec_W2, emb_W2, emb_W3,
                                                     P1, P2, Pq, Po, Pr1, Pr2, Pe2, Pe3);

    embed_mfma_kernel<<<NTOK / 16, 256, 0, stream>>>(inp, mask, emb_W1, emb_b1,
                                                     Pe2, emb_b2, Pe3, emb_b3,
                                                     tok_emb, emb_ln_s, emb_ln_b, x);

    // all-layer positional projections (bf16, MFMA-B layout) + one-time padding zero
    pos_kernel<<<dim3(32, NL), 128, 0, stream>>>(rel_emb, pos_k_W, pos_q_W, pos_q_b, Pkb, Pqb);
    pad_kernel<<<128, 256, 0, stream>>>(qbf, kbf, vTb);

    for (int l = 0; l < NL; l++) {
        qkv_mfma_kernel<<<NTOK / 16, 256, 0, stream>>>(x, Pq + (size_t)l * 49152,
                                                       q_bias + l * 128, v_bias + l * 128,
                                                       qbf, kbf, vTb);
        attn_mfma_kernel<<<dim3(256, 5), 256, 0, stream>>>(qbf, kbf, vTb,
                                                           Pkb + (size_t)l * 2048,
                                                           Pqb + (size_t)l * 2048,
                                                           mask, ctx);
        attnout_mfma_kernel<<<NTOK / 16, 256, 0, stream>>>(ctx, Po + (size_t)l * 16384,
                                                           attn_out_b + l * 128,
                                                           ln1_s + l * 128, ln1_b + l * 128, x);
        ffn_mfma_kernel<<<NTOK / 16, 256, 0, stream>>>(x, P1 + (size_t)l * 65536, ffn_b1 + l * 512,
                                                       P2 + (size_t)l * 65536, ffn_b2 + l * 128,
                                                       ln2_s + l * 128, ln2_b + l * 128, x);
    }

    rec_mfma_kernel<<<NTOK / 16, 256, 0, stream>>>(x, Pr1, rec_b1, Pr2, rec_b2,
                                                   rec_W3, rec_b3, r3b);
    conn_kernel<<<dim3(40, 16), 256, 0, stream>>>(r3b, conn_W, conn_b, d_out, maskw);
}

// Round 5
// 693.171 us; speedup vs baseline: 1.7776x; 1.0545x over previous
//
#include <hip/hip_runtime.h>
#include <hip/hip_bf16.h>
#include <math.h>

#define Bq 64
#define Sq 300
#define NH 4
#define DHd 32
#define Dd 128
#define NL 8
#define FF 512
#define NIN 36
#define SP 304   // padded seq for MFMA tiles
#define SPX 320  // j-range incl. last-tile overrun (10 tiles x 32)

typedef __attribute__((ext_vector_type(8))) short bf16x8;
typedef __attribute__((ext_vector_type(4))) float f32x4;

__device__ __forceinline__ float gelu_f(float x) {
    return 0.5f * x * (1.0f + erff(x * 0.70710678118654752f));
}
__device__ __forceinline__ bool bf16_mode(const unsigned* maskw) {
    return maskw[0] == 0x3F803F80u;   // two bf16 1.0s; f32 1.0 is 0x3F800000
}

// -------- dtype-agnostic input widening: all 36 inputs -> fp32 shadow in ws --------
struct ConvArgs {
    const void* src[NIN];
    float* dst[NIN];
    int n[NIN];
};

__global__ void convert_kernel(ConvArgs a, const unsigned* maskw) {
    bool bfm = bf16_mode(maskw);
    int bi = blockIdx.y;
    int n = a.n[bi];
    float* dst = a.dst[bi];
    int stride = gridDim.x * blockDim.x;
    int i0 = blockIdx.x * blockDim.x + threadIdx.x;
    if (bfm) {
        const __hip_bfloat16* s = (const __hip_bfloat16*)a.src[bi];
        for (int i = i0; i < n; i += stride) dst[i] = __bfloat162float(s[i]);
    } else {
        const float* s = (const float*)a.src[bi];
        for (int i = i0; i < n; i += stride) dst[i] = s[i];
    }
}

// -------- pack weights to MFMA B-operand layout [nt][kt][64][8] bf16 --------
__global__ void pack_kernel(const float* __restrict__ W1all, const float* __restrict__ W2all,
                            const float* __restrict__ Wqall, const float* __restrict__ Woall,
                            const float* __restrict__ Wr1, const float* __restrict__ Wr2,
                            const float* __restrict__ We2, const float* __restrict__ We3,
                            __hip_bfloat16* __restrict__ P1, __hip_bfloat16* __restrict__ P2,
                            __hip_bfloat16* __restrict__ Pq, __hip_bfloat16* __restrict__ Po,
                            __hip_bfloat16* __restrict__ Pr1, __hip_bfloat16* __restrict__ Pr2,
                            __hip_bfloat16* __restrict__ Pe2, __hip_bfloat16* __restrict__ Pe3) {
    int l = blockIdx.y;
    int which = blockIdx.z;
    if (which >= 4 && l != 0) return;
    int K = (which == 1) ? 512 : ((which == 6) ? 64 : 128);
    int N = (which == 0) ? 512 : (which == 1 ? 128 : (which == 2 ? 384 : (which == 5 ? 64 : 128)));
    int slots = (K / 32) * (N / 16) * 64;
    int idx = blockIdx.x * 256 + threadIdx.x;
    if (idx >= slots) return;
    int lane = idx & 63;
    int nkt = K / 32;
    int kt = (idx >> 6) % nkt;
    int nt = (idx >> 6) / nkt;
    const float* W; __hip_bfloat16* P;
    switch (which) {
        case 0:  W = W1all + (size_t)l * 128 * 512; P = P1 + (size_t)l * 65536; break;
        case 1:  W = W2all + (size_t)l * 512 * 128; P = P2 + (size_t)l * 65536; break;
        case 2:  W = Wqall + (size_t)l * 128 * 384; P = Pq + (size_t)l * 49152; break;
        case 3:  W = Woall + (size_t)l * 128 * 128; P = Po + (size_t)l * 16384; break;
        case 4:  W = Wr1; P = Pr1; break;
        case 5:  W = Wr2; P = Pr2; break;
        case 6:  W = We2; P = Pe2; break;
        default: W = We3; P = Pe3; break;
    }
    P += (size_t)idx * 8;
    int n = nt * 16 + (lane & 15);
    int k0 = kt * 32 + (lane >> 4) * 8;
    #pragma unroll
    for (int j = 0; j < 8; j++) P[j] = __float2bfloat16(W[(size_t)(k0 + j) * N + n]);
}

// -------- embedding v3: MFMA for layers 2&3, fp32 layer1 --------
__global__ __launch_bounds__(256) void embed_mfma_kernel(
        const float* __restrict__ inp, const float* __restrict__ mask,
        const float* __restrict__ W1, const float* __restrict__ b1,
        const __hip_bfloat16* __restrict__ Pe2, const float* __restrict__ b2,
        const __hip_bfloat16* __restrict__ Pe3, const float* __restrict__ b3,
        const float* __restrict__ tok_emb,
        const float* __restrict__ ln_s, const float* __restrict__ ln_b,
        float* __restrict__ x) {
    int blk = blockIdx.x;       // 0..1199
    int t = threadIdx.x;        // 0..255
    int w = t >> 6, lane = t & 63;
    int row0 = blk * 16;
    __shared__ float f[16][4];
    __shared__ __align__(16) __hip_bfloat16 e1a[16 * 72];
    __shared__ __align__(16) __hip_bfloat16 e2a[16 * 136];
    __shared__ float dbuf[16 * 132];
    if (t < 64) f[t >> 2][t & 3] = inp[(size_t)(row0 + (t >> 2)) * 4 + (t & 3)];
    __syncthreads();
    {
        int r1 = t >> 4, n0 = (t & 15) * 4;
        float f0 = f[r1][0], f1 = f[r1][1], f2 = f[r1][2];
        #pragma unroll
        for (int j = 0; j < 4; j++) {
            int n = n0 + j;
            float a = b1[n] + f0 * W1[n] + f1 * W1[64 + n] + f2 * W1[128 + n];
            e1a[r1 * 72 + n] = __float2bfloat16(gelu_f(a));
        }
    }
    __syncthreads();
    int m = lane & 15, quad = lane >> 4;
    bf16x8 a2[2];
    #pragma unroll
    for (int kt = 0; kt < 2; kt++) a2[kt] = *(bf16x8*)&e1a[m * 72 + kt * 32 + quad * 8];
    #pragma unroll
    for (int nt0 = 0; nt0 < 2; nt0++) {
        int nt = w * 2 + nt0;
        f32x4 acc = {0.f, 0.f, 0.f, 0.f};
        const bf16x8* bp = (const bf16x8*)(Pe2 + (size_t)nt * 2 * 512);
        #pragma unroll
        for (int kt = 0; kt < 2; kt++) {
            bf16x8 bfr = bp[kt * 64 + lane];
            acc = __builtin_amdgcn_mfma_f32_16x16x32_bf16(a2[kt], bfr, acc, 0, 0, 0);
        }
        int n = nt * 16 + m;
        float bb = b2[n];
        #pragma unroll
        for (int r = 0; r < 4; r++)
            e2a[(quad * 4 + r) * 136 + n] = __float2bfloat16(gelu_f(acc[r] + bb));
    }
    __syncthreads();
    bf16x8 a3[4];
    #pragma unroll
    for (int kt = 0; kt < 4; kt++) a3[kt] = *(bf16x8*)&e2a[m * 136 + kt * 32 + quad * 8];
    f32x4 acc2[2] = {{0.f,0.f,0.f,0.f}, {0.f,0.f,0.f,0.f}};
    #pragma unroll
    for (int kt = 0; kt < 4; kt++) {
        #pragma unroll
        for (int nt0 = 0; nt0 < 2; nt0++) {
            int nt = w * 2 + nt0;
            bf16x8 bfr = ((const bf16x8*)(Pe3 + (size_t)nt * 4 * 512))[kt * 64 + lane];
            acc2[nt0] = __builtin_amdgcn_mfma_f32_16x16x32_bf16(a3[kt], bfr, acc2[nt0], 0, 0, 0);
        }
    }
    #pragma unroll
    for (int nt0 = 0; nt0 < 2; nt0++) {
        int n = (w * 2 + nt0) * 16 + m;
        float bb = b3[n];
        #pragma unroll
        for (int r = 0; r < 4; r++) {
            int row = quad * 4 + r;
            int tok = (int)f[row][3];
            dbuf[row * 132 + n] = gelu_f(acc2[nt0][r] + bb) + tok_emb[tok * 128 + n];
        }
    }
    __syncthreads();
    #pragma unroll
    for (int rr = 0; rr < 4; rr++) {
        int row = w * 4 + rr;
        int c0 = lane, c1 = lane + 64;
        float y0 = dbuf[row * 132 + c0];
        float y1 = dbuf[row * 132 + c1];
        float sm = y0 + y1;
        #pragma unroll
        for (int o = 32; o > 0; o >>= 1) sm += __shfl_xor(sm, o);
        float mu = sm * (1.0f / 128.0f);
        float d0 = y0 - mu, d1 = y1 - mu;
        float vv = d0 * d0 + d1 * d1;
        #pragma unroll
        for (int o = 32; o > 0; o >>= 1) vv += __shfl_xor(vv, o);
        float rstd = rsqrtf(vv * (1.0f / 128.0f) + 1e-7f);
        float mk = mask[row0 + row];
        x[(size_t)(row0 + row) * 128 + c0] = (d0 * rstd * ln_s[c0] + ln_b[c0]) * mk;
        x[(size_t)(row0 + row) * 128 + c1] = (d1 * rstd * ln_s[c1] + ln_b[c1]) * mk;
    }
}

// -------- qkv via MFMA: emits bf16 q/k [bh][SP][32] and vT [bh][32][SP] --------
__global__ __launch_bounds__(256) void qkv_mfma_kernel(const float* __restrict__ x,
                                                       const __hip_bfloat16* __restrict__ Pq,
                                                       const float* __restrict__ qb, const float* __restrict__ vb,
                                                       __hip_bfloat16* __restrict__ qbf,
                                                       __hip_bfloat16* __restrict__ kbf,
                                                       __hip_bfloat16* __restrict__ vT) {
    int blk = blockIdx.x;       // 0..1199
    int t = threadIdx.x;        // 0..255
    int w = t >> 6, lane = t & 63;
    int row0 = blk * 16;
    __shared__ __align__(16) __hip_bfloat16 xa[16 * 136];
    for (int i = t; i < 512; i += 256) {
        float4 v4 = ((const float4*)(x + (size_t)row0 * 128))[i];
        int r = i >> 5, c4 = (i & 31) * 4;
        __hip_bfloat16* d = &xa[r * 136 + c4];
        d[0] = __float2bfloat16(v4.x); d[1] = __float2bfloat16(v4.y);
        d[2] = __float2bfloat16(v4.z); d[3] = __float2bfloat16(v4.w);
    }
    __syncthreads();
    int m = lane & 15, quad = lane >> 4;
    bf16x8 a1[4];
    #pragma unroll
    for (int kt = 0; kt < 4; kt++) a1[kt] = *(bf16x8*)&xa[m * 136 + kt * 32 + quad * 8];
    const float inv_scale = 0.10206207261596576f;  // 1/sqrt(96)
    #pragma unroll
    for (int nt0 = 0; nt0 < 6; nt0++) {
        int nt = w * 6 + nt0;
        f32x4 acc = {0.f, 0.f, 0.f, 0.f};
        const bf16x8* bp = (const bf16x8*)(Pq + (size_t)nt * 4 * 512);
        #pragma unroll
        for (int kt = 0; kt < 4; kt++) {
            bf16x8 bfr = bp[kt * 64 + lane];
            acc = __builtin_amdgcn_mfma_f32_16x16x32_bf16(a1[kt], bfr, acc, 0, 0, 0);
        }
        int n = nt * 16 + m;
        int h = n / 96, mm = (n % 96) / 32, d = n % 32;
        float qbv = qb[h * 32 + d], vbv = vb[h * 32 + d];
        #pragma unroll
        for (int r = 0; r < 4; r++) {
            int row = row0 + quad * 4 + r;
            int bb = row / Sq, s = row % Sq;
            int bh = bb * NH + h;
            float a = acc[r];
            if (mm == 0) {
                qbf[((size_t)bh * SP + s) * 32 + d] = __float2bfloat16((a + qbv) * inv_scale);
            } else if (mm == 1) {
                kbf[((size_t)bh * SP + s) * 32 + d] = __float2bfloat16(a);
            } else {
                vT[((size_t)bh * 32 + d) * SP + s] = __float2bfloat16(a + vbv);
            }
        }
    }
}

// -------- zero the never-written padding rows/cols (once, before layer loop) --------
__global__ void pad_kernel(__hip_bfloat16* qbf, __hip_bfloat16* kbf, __hip_bfloat16* vT) {
    int i = blockIdx.x * 256 + threadIdx.x;   // 256 bh * 4 s * 32 d = 32768
    if (i >= 256 * 4 * 32) return;
    int bh = i >> 7, s = Sq + ((i >> 5) & 3), d = i & 31;
    __hip_bfloat16 z = __float2bfloat16(0.0f);
    qbf[((size_t)bh * SP + s) * 32 + d] = z;
    kbf[((size_t)bh * SP + s) * 32 + d] = z;
    vT[((size_t)bh * 32 + d) * SP + s] = z;
}

// -------- positional projections -> bf16 MFMA-B layout [L][NH][16 r][32 d] --------
__global__ void pos_kernel(const float* __restrict__ rel_emb,
                           const float* __restrict__ pkW_all, const float* __restrict__ pqW_all,
                           const float* __restrict__ pqb_all,
                           __hip_bfloat16* __restrict__ poskb, __hip_bfloat16* __restrict__ posqb) {
    int l = blockIdx.y;         // 0..NL-1
    int bi = blockIdx.x;        // 0..31
    int which = bi >> 4;        // 0: posk, 1: posq
    int r = bi & 15;
    int t = threadIdx.x;        // 0..127 = h*32+d
    __shared__ float re[128];
    re[t] = rel_emb[r * 128 + t];
    __syncthreads();
    const float* W = (which ? pqW_all : pkW_all) + (size_t)l * 128 * 128;
    float a = 0.0f;
    for (int k = 0; k < 128; k++) a += re[k] * W[k * 128 + t];
    int h = t >> 5, d = t & 31;
    size_t o = ((size_t)(l * NH + h) * 16 + r) * 32 + d;
    if (which) { a = (a + pqb_all[l * 128 + t]) * 0.10206207261596576f; posqb[o] = __float2bfloat16(a); }
    else       { poskb[o] = __float2bfloat16(a); }
}

// -------- MFMA attention v2: swapped QK^T, in-kernel c2p/p2c, mask fold; ctx bf16 out --------
__global__ __launch_bounds__(256) void attn_mfma_kernel(const __hip_bfloat16* __restrict__ qbf,
                                                        const __hip_bfloat16* __restrict__ kbf,
                                                        const __hip_bfloat16* __restrict__ vT,
                                                        const __hip_bfloat16* __restrict__ poskb,
                                                        const __hip_bfloat16* __restrict__ posqb,
                                                        const float* __restrict__ mask,
                                                        __hip_bfloat16* __restrict__ ctxb) {
    int bh = blockIdx.x;            // 0..255
    int b = bh >> 2, h = bh & 3;
    int t = threadIdx.x;
    int w = t >> 6, lane = t & 63;
    int m = lane & 15, quad = lane >> 4;

    __shared__ float p2cS[SPX * 17];                        // 21760 B, block-shared
    __shared__ float c2pS[4][16 * 17];                      // per-wave
    __shared__ __align__(16) __hip_bfloat16 pT[4][16 * 40]; // per-wave P, [q][j] layout

    // ---- stage p2cS[j][r] = k[j].posq[r] via MFMA, with mask/padding folded to -3e4 ----
    {
        bf16x8 pqf = *(const bf16x8*)&posqb[(h * 16 + m) * 32 + quad * 8];
        #pragma unroll
        for (int it = 0; it < 5; it++) {
            int jb = (w + it * 4) * 16;
            bf16x8 kf2 = *(const bf16x8*)&kbf[((size_t)bh * SP + jb + m) * 32 + quad * 8];
            f32x4 pc = __builtin_amdgcn_mfma_f32_16x16x32_bf16(kf2, pqf, (f32x4){0.f,0.f,0.f,0.f}, 0, 0, 0);
            #pragma unroll
            for (int r = 0; r < 4; r++) {
                int j = jb + quad * 4 + r;                  // D row = A(K) row
                float mv = (j < Sq) ? mask[b * Sq + j] : 0.0f;
                p2cS[j * 17 + m] = (mv > 0.0f) ? pc[r] : -30000.0f;
            }
        }
    }
    __syncthreads();

    int qt = blockIdx.y * 4 + w;    // 0..19
    if (qt >= 19) return;           // no barriers after this point
    int q0 = qt * 16;

    float* c2pW = c2pS[w];
    __hip_bfloat16* pTW = pT[w];

    bf16x8 aq = *(const bf16x8*)&qbf[((size_t)bh * SP + q0 + m) * 32 + quad * 8];

    // ---- c2pW[q][r] = q[q].posk[r] via one MFMA (wave-private) ----
    {
        bf16x8 pkf = *(const bf16x8*)&poskb[(h * 16 + m) * 32 + quad * 8];
        f32x4 cc = __builtin_amdgcn_mfma_f32_16x16x32_bf16(aq, pkf, (f32x4){0.f,0.f,0.f,0.f}, 0, 0, 0);
        #pragma unroll
        for (int r = 0; r < 4; r++) c2pW[(quad * 4 + r) * 17 + m] = cc[r];
    }

    int qi = q0 + m;                // this lane's q-row (swapped layout)
    f32x4 oacc[2] = {{0.f,0.f,0.f,0.f}, {0.f,0.f,0.f,0.f}};
    float lacc = 0.0f;

    for (int jt2 = 0; jt2 < 10; jt2++) {
        int j0 = jt2 * 32;
        #pragma unroll
        for (int half = 0; half < 2; half++) {
            int jh = j0 + half * 16;
            bf16x8 kf = *(const bf16x8*)&kbf[((size_t)bh * SP + jh + m) * 32 + quad * 8];
            f32x4 sc = __builtin_amdgcn_mfma_f32_16x16x32_bf16(kf, aq, (f32x4){0.f,0.f,0.f,0.f}, 0, 0, 0);
            int jb2 = jh + quad * 4;
            int base = qi - jb2 + 8;
            __hip_bfloat16 pb[4];
            #pragma unroll
            for (int r = 0; r < 4; r++) {
                int rr = base - r; rr = rr < 0 ? 0 : (rr > 15 ? 15 : rr);
                float sv = sc[r] + c2pW[m * 17 + rr] + p2cS[(jb2 + r) * 17 + rr];
                float p = __expf(sv);
                lacc += p;
                pb[r] = __float2bfloat16(p);
            }
            *(uint2*)&pTW[m * 40 + half * 16 + quad * 4] = *(uint2*)pb;   // packed 4x bf16
        }
        bf16x8 ap = *(bf16x8*)&pTW[m * 40 + quad * 8];
        #pragma unroll
        for (int nt = 0; nt < 2; nt++) {
            bf16x8 vf = *(const bf16x8*)&vT[((size_t)bh * 32 + nt * 16 + m) * SP + j0 + quad * 8];
            oacc[nt] = __builtin_amdgcn_mfma_f32_16x16x32_bf16(ap, vf, oacc[nt], 0, 0, 0);
        }
    }

    lacc += __shfl_xor(lacc, 16);
    lacc += __shfl_xor(lacc, 32);
    #pragma unroll
    for (int r = 0; r < 4; r++) {
        int qrow = quad * 4 + r;
        float lr = __shfl(lacc, qrow);
        int qi2 = q0 + qrow;
        float qm = (qi2 < Sq) ? mask[b * Sq + qi2] : 0.0f;
        float inv = (qm > 0.0f && lr > 0.0f) ? 1.0f / lr : 0.0f;
        if (qi2 < Sq) {
            size_t base2 = ((size_t)(b * Sq + qi2)) * 128 + h * 32;
            ctxb[base2 + m]      = __float2bfloat16(oacc[0][r] * inv);
            ctxb[base2 + 16 + m] = __float2bfloat16(oacc[1][r] * inv);
        }
    }
}

// -------- FUSED attn_out + FFN: 16 rows/block; ctx(bf16) -> LN1 -> FFN -> LN2 -> x --------
__global__ __launch_bounds__(256) void aoffn_mfma_kernel(
        const __hip_bfloat16* __restrict__ ctxb,
        const __hip_bfloat16* __restrict__ Po, const float* __restrict__ ob,
        const float* __restrict__ ln1s, const float* __restrict__ ln1b,
        const __hip_bfloat16* __restrict__ P1, const float* __restrict__ b1,
        const __hip_bfloat16* __restrict__ P2, const float* __restrict__ b2,
        const float* __restrict__ ln2s, const float* __restrict__ ln2b,
        float* __restrict__ x) {
    int blk = blockIdx.x;       // 0..1199
    int t = threadIdx.x;        // 0..255
    int w = t >> 6, lane = t & 63;
    int row0 = blk * 16;

    __shared__ __align__(16) __hip_bfloat16 ca[16 * 136];  // ctx A-layout; reused as x1 A-layout
    __shared__ float xr[16 * 128];                         // residual (x, then x1)
    __shared__ __align__(16) __hip_bfloat16 ha[16 * 520];  // FFN hidden
    __shared__ float dbuf[16 * 132];

    {   // stage ctx (bf16, direct copy) + x (fp32 residual)
        uint4 cv = ((const uint4*)(ctxb + (size_t)row0 * 128))[t];   // 256 x 8 bf16
        int r = t >> 4, c8 = (t & 15) * 8;
        *(uint4*)&ca[r * 136 + c8] = cv;
    }
    for (int i = t; i < 512; i += 256) {
        float4 xv4 = ((const float4*)(x + (size_t)row0 * 128))[i];
        int r = i >> 5, c4 = (i & 31) * 4;
        *(float4*)&xr[r * 128 + c4] = xv4;
    }
    __syncthreads();

    int m = lane & 15, quad = lane >> 4;

    // ---- attn_out matmul: K=128, N=128 ----
    {
        bf16x8 a1[4];
        #pragma unroll
        for (int kt = 0; kt < 4; kt++) a1[kt] = *(bf16x8*)&ca[m * 136 + kt * 32 + quad * 8];
        f32x4 acc2[2] = {{0.f,0.f,0.f,0.f}, {0.f,0.f,0.f,0.f}};
        #pragma unroll
        for (int kt = 0; kt < 4; kt++) {
            #pragma unroll
            for (int nt0 = 0; nt0 < 2; nt0++) {
                int nt = w * 2 + nt0;
                bf16x8 bfr = ((const bf16x8*)(Po + (size_t)nt * 4 * 512))[kt * 64 + lane];
                acc2[nt0] = __builtin_amdgcn_mfma_f32_16x16x32_bf16(a1[kt], bfr, acc2[nt0], 0, 0, 0);
            }
        }
        #pragma unroll
        for (int nt0 = 0; nt0 < 2; nt0++) {
            int n = (w * 2 + nt0) * 16 + m;
            #pragma unroll
            for (int r = 0; r < 4; r++) dbuf[(quad * 4 + r) * 132 + n] = acc2[nt0][r];
        }
    }
    __syncthreads();

    // ---- LN1 (+residual) -> x1 into ca (bf16 A-layout) and xr (fp32, in place) ----
    #pragma unroll
    for (int rr = 0; rr < 4; rr++) {
        int row = w * 4 + rr;
        int c0 = lane, c1 = lane + 64;
        float y0 = dbuf[row * 132 + c0] + ob[c0] + xr[row * 128 + c0];
        float y1 = dbuf[row * 132 + c1] + ob[c1] + xr[row * 128 + c1];
        float sm = y0 + y1;
        #pragma unroll
        for (int o = 32; o > 0; o >>= 1) sm += __shfl_xor(sm, o);
        float mu = sm * (1.0f / 128.0f);
        float d0 = y0 - mu, d1 = y1 - mu;
        float vv = d0 * d0 + d1 * d1;
        #pragma unroll
        for (int o = 32; o > 0; o >>= 1) vv += __shfl_xor(vv, o);
        float rstd = rsqrtf(vv * (1.0f / 128.0f) + 1e-7f);
        float o0 = d0 * rstd * ln1s[c0] + ln1b[c0];
        float o1 = d1 * rstd * ln1s[c1] + ln1b[c1];
        xr[row * 128 + c0] = o0;
        xr[row * 128 + c1] = o1;
        ca[row * 136 + c0] = __float2bfloat16(o0);
        ca[row * 136 + c1] = __float2bfloat16(o1);
    }
    __syncthreads();

    // ---- FFN phase 1: h = gelu(x1 @ W1 + b1); N=512, 8 n-tiles/wave ----
    {
        bf16x8 a1[4];
        #pragma unroll
        for (int kt = 0; kt < 4; kt++) a1[kt] = *(bf16x8*)&ca[m * 136 + kt * 32 + quad * 8];
        #pragma unroll
        for (int nt0 = 0; nt0 < 8; nt0++) {
            int nt = w * 8 + nt0;
            f32x4 acc = {0.f, 0.f, 0.f, 0.f};
            const bf16x8* bp = (const bf16x8*)(P1 + (size_t)nt * 4 * 512);
            #pragma unroll
            for (int kt = 0; kt < 4; kt++) {
                bf16x8 bfr = bp[kt * 64 + lane];
                acc = __builtin_amdgcn_mfma_f32_16x16x32_bf16(a1[kt], bfr, acc, 0, 0, 0);
            }
            int n = nt * 16 + m;
            float bb = b1[n];
            #pragma unroll
            for (int r = 0; r < 4; r++)
                ha[(quad * 4 + r) * 520 + n] = __float2bfloat16(gelu_f(acc[r] + bb));
        }
    }
    __syncthreads();

    // ---- FFN phase 2: K=512, N=128 ----
    {
        f32x4 acc2[2] = {{0.f,0.f,0.f,0.f}, {0.f,0.f,0.f,0.f}};
        #pragma unroll
        for (int kt = 0; kt < 16; kt++) {
            bf16x8 a = *(bf16x8*)&ha[m * 520 + kt * 32 + quad * 8];
            #pragma unroll
            for (int nt0 = 0; nt0 < 2; nt0++) {
                int nt = w * 2 + nt0;
                bf16x8 bfr = ((const bf16x8*)(P2 + (size_t)nt * 16 * 512))[kt * 64 + lane];
                acc2[nt0] = __builtin_amdgcn_mfma_f32_16x16x32_bf16(a, bfr, acc2[nt0], 0, 0, 0);
            }
        }
        #pragma unroll
        for (int nt0 = 0; nt0 < 2; nt0++) {
            int n = (w * 2 + nt0) * 16 + m;
            #pragma unroll
            for (int r = 0; r < 4; r++)
                dbuf[(quad * 4 + r) * 132 + n] = acc2[nt0][r];
        }
    }
    __syncthreads();

    // ---- LN2 (+residual x1) -> x global ----
    #pragma unroll
    for (int rr = 0; rr < 4; rr++) {
        int row = w * 4 + rr;
        int c0 = lane, c1 = lane + 64;
        float y0 = dbuf[row * 132 + c0] + b2[c0] + xr[row * 128 + c0];
        float y1 = dbuf[row * 132 + c1] + b2[c1] + xr[row * 128 + c1];
        float sm = y0 + y1;
        #pragma unroll
        for (int o = 32; o > 0; o >>= 1) sm += __shfl_xor(sm, o);
        float mu = sm * (1.0f / 128.0f);
        float d0 = y0 - mu, d1 = y1 - mu;
        float vv = d0 * d0 + d1 * d1;
        #pragma unroll
        for (int o = 32; o > 0; o >>= 1) vv += __shfl_xor(vv, o);
        float rstd = rsqrtf(vv * (1.0f / 128.0f) + 1e-7f);
        x[(size_t)(row0 + row) * 128 + c0] = d0 * rstd * ln2s[c0] + ln2b[c0];
        x[(size_t)(row0 + row) * 128 + c1] = d1 * rstd * ln2s[c1] + ln2b[c1];
    }
}

// -------- reconstruction MLP via MFMA: 16 rows/block; 128->128->64->5 --------
__global__ __launch_bounds__(256) void rec_mfma_kernel(const float* __restrict__ x,
                                                       const __hip_bfloat16* __restrict__ Pr1,
                                                       const float* __restrict__ b1,
                                                       const __hip_bfloat16* __restrict__ Pr2,
                                                       const float* __restrict__ b2,
                                                       const float* __restrict__ W3, const float* __restrict__ b3,
                                                       float* __restrict__ r3) {
    int blk = blockIdx.x;       // 0..1199
    int t = threadIdx.x;        // 0..255
    int w = t >> 6, lane = t & 63;
    int row0 = blk * 16;
    __shared__ __align__(16) __hip_bfloat16 xa[16 * 136];
    __shared__ __align__(16) __hip_bfloat16 ha[16 * 136];
    __shared__ float r2s[16 * 68];
    for (int i = t; i < 512; i += 256) {
        float4 v4 = ((const float4*)(x + (size_t)row0 * 128))[i];
        int r = i >> 5, c4 = (i & 31) * 4;
        __hip_bfloat16* d = &xa[r * 136 + c4];
        d[0] = __float2bfloat16(v4.x); d[1] = __float2bfloat16(v4.y);
        d[2] = __float2bfloat16(v4.z); d[3] = __float2bfloat16(v4.w);
    }
    __syncthreads();
    int m = lane & 15, quad = lane >> 4;

    bf16x8 a1[4];
    #pragma unroll
    for (int kt = 0; kt < 4; kt++) a1[kt] = *(bf16x8*)&xa[m * 136 + kt * 32 + quad * 8];
    #pragma unroll
    for (int nt0 = 0; nt0 < 2; nt0++) {
        int nt = w * 2 + nt0;
        f32x4 acc = {0.f, 0.f, 0.f, 0.f};
        const bf16x8* bp = (const bf16x8*)(Pr1 + (size_t)nt * 4 * 512);
        #pragma unroll
        for (int kt = 0; kt < 4; kt++) {
            bf16x8 bfr = bp[kt * 64 + lane];
            acc = __builtin_amdgcn_mfma_f32_16x16x32_bf16(a1[kt], bfr, acc, 0, 0, 0);
        }
        int n = nt * 16 + m;
        float bb = b1[n];
        #pragma unroll
        for (int r = 0; r < 4; r++)
            ha[(quad * 4 + r) * 136 + n] = __float2bfloat16(gelu_f(acc[r] + bb));
    }
    __syncthreads();

    {
        f32x4 acc = {0.f, 0.f, 0.f, 0.f};
        const bf16x8* bp = (const bf16x8*)(Pr2 + (size_t)w * 4 * 512);
        #pragma unroll
        for (int kt = 0; kt < 4; kt++) {
            bf16x8 a = *(bf16x8*)&ha[m * 136 + kt * 32 + quad * 8];
            bf16x8 bfr = bp[kt * 64 + lane];
            acc = __builtin_amdgcn_mfma_f32_16x16x32_bf16(a, bfr, acc, 0, 0, 0);
        }
        int n = w * 16 + m;
        float bb = b2[n];
        #pragma unroll
        for (int r = 0; r < 4; r++)
            r2s[(quad * 4 + r) * 68 + n] = gelu_f(acc[r] + bb);
    }
    __syncthreads();

    if (t < 80) {
        int row = t / 5, c = t % 5;
        float a = b3[c];
        for (int k = 0; k < 64; k++) a += r2s[row * 68 + k] * W3[k * 5 + c];
        r3[(size_t)(row0 + row) * 5 + c] = gelu_f(a);
    }
}

// -------- connection head v2 (R15 win, unchanged) --------
__global__ void conn_kernel(const float* __restrict__ r3, const float* __restrict__ W,
                            const float* __restrict__ b, void* out, const unsigned* maskw) {
    bool bfm = bf16_mode(maskw);
    int cb = blockIdx.x;     // 0..39
    int bg = blockIdx.y;     // 0..15
    int t = threadIdx.x;     // 0..255
    int cl = t & 63;
    int kq = t >> 6;
    int col = cb * 64 + cl;
    __shared__ float rs[4 * 1500];
    __shared__ float pacc[4 * 64 * 4];
    {
        const float4* src = (const float4*)(r3 + (size_t)bg * 4 * 1500);
        for (int i = t; i < 1500; i += 256) ((float4*)rs)[i] = src[i];
    }
    __syncthreads();
    float acc[4] = {0.f, 0.f, 0.f, 0.f};
    if (col < 2500) {
        for (int k = kq * 4; k < 1500; k += 16) {
            float w0 = W[(size_t)(k + 0) * 2500 + col];
            float w1 = W[(size_t)(k + 1) * 2500 + col];
            float w2 = W[(size_t)(k + 2) * 2500 + col];
            float w3 = W[(size_t)(k + 3) * 2500 + col];
            #pragma unroll
            for (int bb = 0; bb < 4; bb++) {
                float4 rv = *(const float4*)&rs[bb * 1500 + k];
                acc[bb] += rv.x * w0 + rv.y * w1 + rv.z * w2 + rv.w * w3;
            }
        }
    }
    #pragma unroll
    for (int bb = 0; bb < 4; bb++) pacc[(kq * 64 + cl) * 4 + bb] = acc[bb];
    __syncthreads();
    if (kq == 0 && col < 2500) {
        float bv = b[col];
        #pragma unroll
        for (int bb = 0; bb < 4; bb++) {
            float a = bv + pacc[(0 * 64 + cl) * 4 + bb] + pacc[(1 * 64 + cl) * 4 + bb]
                         + pacc[(2 * 64 + cl) * 4 + bb] + pacc[(3 * 64 + cl) * 4 + bb];
            int ob = bg * 4 + bb;
            if (bfm) ((__hip_bfloat16*)out)[(size_t)ob * 2500 + col] = __float2bfloat16(a);
            else     ((float*)out)[(size_t)ob * 2500 + col] = a;
        }
    }
}

extern "C" void kernel_launch(void* const* d_in, const int* in_sizes, int n_in,
                              void* d_out, int out_size, void* d_ws, size_t ws_size,
                              hipStream_t stream) {
    float* ws = (float*)d_ws;

    float* cv[NIN];
    size_t off = 0;
    for (int i = 0; i < NIN; i++) { cv[i] = ws + off; off += (size_t)in_sizes[i]; }

    const float* inp      = cv[0];
    const float* mask     = cv[1];
    const float* emb_W1   = cv[2];
    const float* emb_b1   = cv[3];
    const float* emb_W2   = cv[4];
    const float* emb_b2   = cv[5];
    const float* emb_W3   = cv[6];
    const float* emb_b3   = cv[7];
    const float* tok_emb  = cv[8];
    const float* emb_ln_s = cv[9];
    const float* emb_ln_b = cv[10];
    const float* rel_emb  = cv[11];
    const float* qkv_W    = cv[12];
    const float* q_bias   = cv[13];
    const float* v_bias   = cv[14];
    const float* pos_k_W  = cv[15];
    const float* pos_q_W  = cv[16];
    const float* pos_q_b  = cv[17];
    const float* attn_out_W = cv[18];
    const float* attn_out_b = cv[19];
    const float* ln1_s    = cv[20];
    const float* ln1_b    = cv[21];
    const float* ffn_W1   = cv[22];
    const float* ffn_b1   = cv[23];
    const float* ffn_W2   = cv[24];
    const float* ffn_b2   = cv[25];
    const float* ln2_s    = cv[26];
    const float* ln2_b    = cv[27];
    const float* rec_W1   = cv[28];
    const float* rec_b1   = cv[29];
    const float* rec_W2   = cv[30];
    const float* rec_b2   = cv[31];
    const float* rec_W3   = cv[32];
    const float* rec_b3   = cv[33];
    const float* conn_W   = cv[34];
    const float* conn_b   = cv[35];

    const int NTOK = Bq * Sq;            // 19200
    float* x    = ws + off;
    float* q    = x    + (size_t)NTOK * 128;             // (unused, kept for layout)
    float* k    = q    + (size_t)Bq * NH * Sq * 32;      // (unused)
    float* ctx  = k    + (size_t)Bq * NH * Sq * 32;      // reused as bf16 ctx
    float* c2p  = ctx  + (size_t)NTOK * 128;             // (unused)
    float* p2c  = c2p  + (size_t)Bq * NH * Sq * 16;      // (unused)
    float* posk = p2c  + (size_t)Bq * NH * Sq * 16;      // (unused)
    float* posq = posk + (size_t)NL * 16 * 128;          // (unused)
    float* r3b  = posq + (size_t)NL * 16 * 128;
    float* endf = r3b  + (size_t)NTOK * 5;
    __hip_bfloat16* P1 = (__hip_bfloat16*)endf;          // 8 x 65536 bf16
    __hip_bfloat16* P2 = P1 + (size_t)NL * 65536;
    __hip_bfloat16* Pq = P2 + (size_t)NL * 65536;        // 8 x 49152
    __hip_bfloat16* Po = Pq + (size_t)NL * 49152;        // 8 x 16384
    __hip_bfloat16* qbf = Po + (size_t)NL * 16384;       // 256*SP*32 each
    __hip_bfloat16* kbf = qbf + (size_t)256 * SP * 32;
    __hip_bfloat16* vTb = kbf + (size_t)256 * SP * 32;
    __hip_bfloat16* Pr1 = vTb + (size_t)256 * SP * 32;   // 16384
    __hip_bfloat16* Pr2 = Pr1 + 16384;                   // 8192
    __hip_bfloat16* Pe2 = Pr2 + 8192;                    // 8192
    __hip_bfloat16* Pe3 = Pe2 + 8192;                    // 16384
    __hip_bfloat16* Pkb = Pe3 + 16384;                   // [NL][NH][16][32] = 16384
    __hip_bfloat16* Pqb = Pkb + (size_t)NL * 2048;       // same
    __hip_bfloat16* ctxb = (__hip_bfloat16*)ctx;         // bf16 ctx [NTOK][128]

    const unsigned* maskw = (const unsigned*)d_in[1];

    ConvArgs ca;
    for (int i = 0; i < NIN; i++) {
        ca.src[i] = d_in[i];
        ca.dst[i] = cv[i];
        ca.n[i] = in_sizes[i];
    }
    convert_kernel<<<dim3(256, NIN), 256, 0, stream>>>(ca, maskw);
    pack_kernel<<<dim3(32, NL, 8), 256, 0, stream>>>(ffn_W1, ffn_W2, qkv_W, attn_out_W,
                                                     rec_W1, rec_W2, emb_W2, emb_W3,
                                                     P1, P2, Pq, Po, Pr1, Pr2, Pe2, Pe3);

    embed_mfma_kernel<<<NTOK / 16, 256, 0, stream>>>(inp, mask, emb_W1, emb_b1,
                                                     Pe2, emb_b2, Pe3, emb_b3,
                                                     tok_emb, emb_ln_s, emb_ln_b, x);

    pos_kernel<<<dim3(32, NL), 128, 0, stream>>>(rel_emb, pos_k_W, pos_q_W, pos_q_b, Pkb, Pqb);
    pad_kernel<<<128, 256, 0, stream>>>(qbf, kbf, vTb);

    for (int l = 0; l < NL; l++) {
        qkv_mfma_kernel<<<NTOK / 16, 256, 0, stream>>>(x, Pq + (size_t)l * 49152,
                                                       q_bias + l * 128, v_bias + l * 128,
                                                       qbf, kbf, vTb);
        attn_mfma_kernel<<<dim3(256, 5), 256, 0, stream>>>(qbf, kbf, vTb,
                                                           Pkb + (size_t)l * 2048,
                                                           Pqb + (size_t)l * 2048,
                                                           mask, ctxb);
        aoffn_mfma_kernel<<<NTOK / 16, 256, 0, stream>>>(ctxb,
                                                         Po + (size_t)l * 16384, attn_out_b + l * 128,
                                                         ln1_s + l * 128, ln1_b + l * 128,
                                                         P1 + (size_t)l * 65536, ffn_b1 + l * 512,
                                                         P2 + (size_t)l * 65536, ffn_b2 + l * 128,
                                                         ln2_s + l * 128, ln2_b + l * 128, x);
    }

    rec_mfma_kernel<<<NTOK / 16, 256, 0, stream>>>(x, Pr1, rec_b1, Pr2, rec_b2,
                                                   rec_W3, rec_b3, r3b);
    conn_kernel<<<dim3(40, 16), 256, 0, stream>>>(r3b, conn_W, conn_b, d_out, maskw);
}